// Round 9
// baseline (2889.547 us; speedup 1.0000x reference)
//
#include <hip/hip_runtime.h>
#include <math.h>

#define Bb 256
#define Ii 128
#define Tt 256
#define Hh 512
#define Oo 2
#define TBr (Tt*Bb)
#define EPS_BN 1e-5f

typedef __attribute__((ext_vector_type(8))) short short8;
typedef __attribute__((ext_vector_type(8))) __bf16 bf16x8;
typedef __attribute__((ext_vector_type(4))) float f32x4;
typedef unsigned long long u64;

__device__ __forceinline__ f32x4 mfma_bf16(short8 a, short8 b, f32x4 c) {
    return __builtin_amdgcn_mfma_f32_16x16x32_bf16(
        __builtin_bit_cast(bf16x8, a), __builtin_bit_cast(bf16x8, b), c, 0, 0, 0);
}
__device__ __forceinline__ short f2bf(float f) {
    union { float f; unsigned u; } v; v.f = f;
    unsigned r = (v.u + 0x7FFFu + ((v.u >> 16) & 1u)) >> 16;
    return (short)r;
}
__device__ __forceinline__ float bf2f(short s) {
    union { unsigned u; float f; } v; v.u = ((unsigned)(unsigned short)s) << 16;
    return v.f;
}
__device__ __forceinline__ float sigmoidf_(float x) { return 1.f / (1.f + expf(-x)); }
__device__ __forceinline__ float softplusf_(float x) { return fmaxf(x, 0.f) + log1pf(expf(-fabsf(x))); }

#define ALD_F(p)  __hip_atomic_load((p),  __ATOMIC_RELAXED, __HIP_MEMORY_SCOPE_AGENT)
#define AST_F(p,v) __hip_atomic_store((p), (v), __ATOMIC_RELAXED, __HIP_MEMORY_SCOPE_AGENT)
#define AADD_F(p,v) (void)__hip_atomic_fetch_add((p), (v), __ATOMIC_RELAXED, __HIP_MEMORY_SCOPE_AGENT)

__device__ __forceinline__ short8 ald16(const short* p) {
    union { u64 u[2]; short8 s; } v;
    v.u[0] = ALD_F((const u64*)p);
    v.u[1] = ALD_F((const u64*)(p + 4));
    return v.s;
}
__device__ __forceinline__ u64 pack4bf(float a, float b, float c_, float d) {
    return (u64)(unsigned short)f2bf(a)
         | ((u64)(unsigned short)f2bf(b) << 16)
         | ((u64)(unsigned short)f2bf(c_) << 32)
         | ((u64)(unsigned short)f2bf(d) << 48);
}

// ---------------------------------------------------------------------------
// repack: input [B,3,I,T] fp32 -> time-major X fp32 [T,B,I], M bf16, D bf16
// ---------------------------------------------------------------------------
__global__ __launch_bounds__(1024) void repack_kernel(const float* __restrict__ in,
                                                      float* __restrict__ Xall,
                                                      short* __restrict__ Mall,
                                                      short* __restrict__ Dall)
{
    __shared__ float tile[32][33];
    const int bz = blockIdx.z;
    const int b = bz / 3, cch = bz % 3;
    const int t0 = blockIdx.x * 32, i0 = blockIdx.y * 32;
    const int tx = threadIdx.x, ty = threadIdx.y;
    const float* src = in + ((size_t)b * 3 + cch) * (size_t)Ii * Tt;
    tile[ty][tx] = src[(size_t)(i0 + ty) * Tt + t0 + tx];
    __syncthreads();
    const float v = tile[tx][ty];
    const size_t off = ((size_t)(t0 + ty) * Bb + b) * Ii + i0 + tx;
    if (cch == 0)      Xall[off] = v;
    else if (cch == 1) Mall[off] = f2bf(v);
    else               Dall[off] = f2bf(v);
}

// ---------------------------------------------------------------------------
// pack weights -> bf16 transposed (n-major, k rows) for MFMA fragments
// ---------------------------------------------------------------------------
__global__ __launch_bounds__(256) void pack_weights_kernel(
    const float* __restrict__ W_dg_x, const float* __restrict__ W_dg_h,
    const float* __restrict__ W_xz, const float* __restrict__ W_hz, const float* __restrict__ W_mz, const float* __restrict__ b_z,
    const float* __restrict__ W_xr, const float* __restrict__ W_hr, const float* __restrict__ W_mr, const float* __restrict__ b_r,
    const float* __restrict__ W_xh, const float* __restrict__ W_hh, const float* __restrict__ W_mh,
    short* __restrict__ Wc1T, short* __restrict__ Wc2T,
    short* __restrict__ WdgxT, short* __restrict__ WdghT, float* __restrict__ bias1)
{
    const int idx = blockIdx.x * blockDim.x + threadIdx.x;
    const int n1 = 1024 * 768, n2 = 512 * 768, n3 = 128 * 128, n4 = 512 * 128;
    if (idx < n1) {
        const int n = idx / 768, k = idx % 768;
        const int col = (n < Hh) ? n : (n - Hh);
        const float* Wx = (n < Hh) ? W_xz : W_xr;
        const float* Wm = (n < Hh) ? W_mz : W_mr;
        const float* Wh = (n < Hh) ? W_hz : W_hr;
        float v;
        if (k < Ii)        v = Wx[(size_t)k * Hh + col];
        else if (k < 2*Ii) v = Wm[(size_t)(k - Ii) * Hh + col];
        else               v = Wh[(size_t)(k - 2*Ii) * Hh + col];
        Wc1T[idx] = f2bf(v);
    } else if (idx < n1 + n2) {
        const int j = idx - n1;
        const int n = j / 768, k = j % 768;
        float v;
        if (k < Ii)        v = W_xh[(size_t)k * Hh + n];
        else if (k < 2*Ii) v = W_mh[(size_t)(k - Ii) * Hh + n];
        else               v = W_hh[(size_t)(k - 2*Ii) * Hh + n];
        Wc2T[j] = f2bf(v);
    } else if (idx < n1 + n2 + n3) {
        const int j = idx - n1 - n2;
        const int n = j >> 7, k = j & 127;
        WdgxT[j] = f2bf(W_dg_x[(size_t)k * Ii + n]);
    } else if (idx < n1 + n2 + n3 + n4) {
        const int j = idx - n1 - n2 - n3;
        const int n = j >> 7, k = j & 127;
        WdghT[j] = f2bf(W_dg_h[(size_t)k * Hh + n]);
    } else if (idx < n1 + n2 + n3 + n4 + 1024) {
        const int n = idx - n1 - n2 - n3 - n4;
        bias1[n] = (n < Hh) ? b_z[n] : b_r[n - Hh];
    }
}

// ---------------------------------------------------------------------------
// gdecay: C = bf16(exp(-relu(A @ B + bias)))
// ---------------------------------------------------------------------------
__global__ __launch_bounds__(64) void gdecay_kernel(const short* __restrict__ A,
                                                    const short* __restrict__ BT,
                                                    const float* __restrict__ bias,
                                                    short* __restrict__ C, int N)
{
    const int lane = threadIdx.x;
    const int c = lane & 15, g = lane >> 4;
    const int m0 = blockIdx.x * 32, n0 = blockIdx.y * 64;
    const short* a0 = A + (size_t)(m0 + c) * Ii + 8 * g;
    const short* a1 = a0 + (size_t)16 * Ii;
    const short* bw = BT + (size_t)(n0 + c) * Ii + 8 * g;
    f32x4 acc[2][4];
    #pragma unroll
    for (int i = 0; i < 2; ++i)
        #pragma unroll
        for (int f = 0; f < 4; ++f) acc[i][f] = (f32x4){0.f, 0.f, 0.f, 0.f};
    #pragma unroll
    for (int k0 = 0; k0 < 128; k0 += 32) {
        const short8 av0 = *(const short8*)(a0 + k0);
        const short8 av1 = *(const short8*)(a1 + k0);
        #pragma unroll
        for (int fn = 0; fn < 4; ++fn) {
            const short8 bv = *(const short8*)(bw + (size_t)fn * 16 * Ii + k0);
            acc[0][fn] = mfma_bf16(av0, bv, acc[0][fn]);
            acc[1][fn] = mfma_bf16(av1, bv, acc[1][fn]);
        }
    }
    #pragma unroll
    for (int fn = 0; fn < 4; ++fn) {
        const int n = n0 + fn * 16 + c;
        const float bs = bias[n];
        #pragma unroll
        for (int fm = 0; fm < 2; ++fm) {
            #pragma unroll
            for (int j = 0; j < 4; ++j) {
                const int m = m0 + fm * 16 + 4 * g + j;
                const float v = expf(-fmaxf(acc[fm][fn][j] + bs, 0.f));
                C[(size_t)m * N + n] = f2bf(v);
            }
        }
    }
}

// ---------------------------------------------------------------------------
// x_last scan + x_eff -> Xe bf16 [T,B,I]
// ---------------------------------------------------------------------------
__global__ __launch_bounds__(256) void xeff_scan_kernel(const float* __restrict__ Xall,
                                                        const short* __restrict__ Mall,
                                                        const short* __restrict__ Gx,
                                                        const float* __restrict__ xmean_p,
                                                        short* __restrict__ Xe)
{
    const int bi = blockIdx.x * blockDim.x + threadIdx.x;
    if (bi >= Bb * Ii) return;
    const float xm = xmean_p[0];
    float xl = 0.f;
    for (int t = 0; t < Tt; ++t) {
        const size_t off = (size_t)t * Bb * Ii + bi;
        const float x = Xall[off];
        const float m = bf2f(Mall[off]);
        const float gx = bf2f(Gx[off]);
        if (m > 0.f) xl = x;
        Xe[off] = f2bf(m * x + (1.f - m) * (gx * xl + (1.f - gx) * xm));
    }
}

// ---------------------------------------------------------------------------
// persistent: 256 blocks x 1024 thr (16 waves). block (mt = bid&15, ng = bid>>4)
// rows m0=mt*16..+16; z cols ng*32; r cols 512+ng*32; htilde cols ng*32.
// A: colt=w&3 (2 z + 2 r tiles), kh=w>>2 (4-way K-split, wA[6]).
// B: colt2=w&1, kq=w>>1 (8-way K-split, wB[3]).
// All waves dump partials to scratch[tid*4]; flat balanced epilogues.
// bar1 = same-mt sub-barrier (rhG); bar2 = global (stats + HrawG).
// ---------------------------------------------------------------------------
#define XM_STR 264
#define HP_STR 520
#define GH_STR 520

__global__ __launch_bounds__(1024, 4) void grud_persistent(
    const short* __restrict__ Xe, const short* __restrict__ Ma,
    const short* __restrict__ Ghb,
    const short* __restrict__ Wc1T, const short* __restrict__ Wc2T,
    const float* __restrict__ bias1, const float* __restrict__ b_h,
    const float* __restrict__ bn_g, const float* __restrict__ bn_b,
    const float* __restrict__ Why, const float* __restrict__ bhy,
    short* __restrict__ rhG,          // [256][512] bf16  (atomic-only)
    short* __restrict__ HrawG,        // [256][512] bf16  (atomic-only)
    float* __restrict__ PstSum,       // [3][1024] f32    (atomic-only)
    int* __restrict__ f1,             // [256][16] int    (atomic-only)
    int* __restrict__ f2,             // [256][16] int    (atomic-only)
    float* __restrict__ out_hs, float* __restrict__ out_ys)
{
    const int bid = blockIdx.x, tid = threadIdx.x;
    const int w = tid >> 6, lane = tid & 63, c = lane & 15, g = lane >> 4;
    const int mt = bid & 15, ng = bid >> 4;
    const int m0 = mt * 16;

    __shared__ short sXM[16 * XM_STR];       // 8.4 KB
    __shared__ short sHP[16 * HP_STR];       // 16.6 KB
    __shared__ short sGH[16 * GH_STR];       // 16.6 KB
    __shared__ float sZ[32 * 17];            // 2.2 KB  [localcol][row]
    __shared__ float scratch[4096];          // 16 KB   [wave][lane][4]
    __shared__ float sWhy[1024];             // 4 KB
    __shared__ float scs[512], shs[512];     // 4 KB
    __shared__ float ysred[32];

    if (tid < 512) { sWhy[tid] = Why[tid]; sWhy[tid + 512] = Why[tid + 512]; }
    const float bhy0 = bhy[0], bhy1 = bhy[1];

    const int colt = w & 3, kh = w >> 2;             // phase A role
    const int colbaseA = (colt < 2) ? (ng * 32 + colt * 16)
                                    : (512 + ng * 32 + (colt - 2) * 16);
    short8 wA[6];
    {
        const short* bw = Wc1T + (size_t)(colbaseA + c) * 768 + kh * 192 + 8 * g;
        #pragma unroll
        for (int s = 0; s < 6; ++s) wA[s] = *(const short8*)(bw + 32 * s);
    }
    const int colt2 = w & 1, kq = w >> 1;            // phase B role
    const int colbaseB = ng * 32 + colt2 * 16;
    short8 wB[3];
    {
        const short* bw = Wc2T + (size_t)(colbaseB + c) * 768 + kq * 96 + 8 * g;
        #pragma unroll
        for (int s = 0; s < 3; ++s) wB[s] = *(const short8*)(bw + 32 * s);
    }
    // ---- stage [Xe|Ma] for t=0 ----
    if (tid < 512) {
        const int r = tid >> 5, cu = tid & 31;
        const short* src = (cu < 16)
            ? (Xe + ((size_t)(m0 + r)) * Ii + 8 * cu)
            : (Ma + ((size_t)(m0 + r)) * Ii + 8 * (cu - 16));
        *(short8*)(&sXM[r * XM_STR + 8 * cu]) = *(const short8*)src;
    }
    __syncthreads();

    for (int t = 0; t < Tt; ++t) {
        // ======= loop-top: [Xe|Ma]-only MFMA partials ======================
        f32x4 accA = (f32x4){0.f, 0.f, 0.f, 0.f};
        f32x4 accB = (f32x4){0.f, 0.f, 0.f, 0.f};
        if (kh == 0) {
            #pragma unroll
            for (int s = 0; s < 6; ++s)
                accA = mfma_bf16(wA[s],
                    *(const short8*)(&sXM[c * XM_STR + 32 * s + 8 * g]), accA);
        } else if (kh == 1) {
            #pragma unroll
            for (int s = 0; s < 2; ++s)
                accA = mfma_bf16(wA[s],
                    *(const short8*)(&sXM[c * XM_STR + 192 + 32 * s + 8 * g]), accA);
        }
        if (kq <= 1) {
            #pragma unroll
            for (int s = 0; s < 3; ++s)
                accB = mfma_bf16(wB[s],
                    *(const short8*)(&sXM[c * XM_STR + kq * 96 + 32 * s + 8 * g]), accB);
        } else if (kq == 2) {
            #pragma unroll
            for (int s = 0; s < 2; ++s)
                accB = mfma_bf16(wB[s],
                    *(const short8*)(&sXM[c * XM_STR + 192 + 32 * s + 8 * g]), accB);
        }

        // ======= stage: BN(t-1) scale/shift, hp, out_hs(t-1), ys(t-1) ======
        if (t > 0) {
            const int pR = (t + 2) % 3;               // (t-1) mod 3
            if (tid < 512) {
                const float s1 = ALD_F(&PstSum[pR * 1024 + tid]);
                const float s2 = ALD_F(&PstSum[pR * 1024 + 512 + tid]);
                const float mu = s1 * (1.f / 256.f);
                const float var = fmaxf(s2 * (1.f / 256.f) - mu * mu, 0.f);
                const float sc = bn_g[tid] * rsqrtf(var + EPS_BN);
                scs[tid] = sc; shs[tid] = bn_b[tid] - mu * sc;
            }
            __syncthreads();
            float p0 = 0.f, p1 = 0.f;
            #pragma unroll
            for (int i = 0; i < 2; ++i) {
                const int idx = tid + i * 1024;       // u64 granule in 16x128
                const int r = idx >> 7, c4 = (idx & 127) * 4;
                union { u64 u; unsigned short us[4]; } hv, gv;
                hv.u = ALD_F((const u64*)(HrawG + (size_t)(m0 + r) * Hh + c4));
                gv.u = *(const u64*)(&sGH[r * GH_STR + c4]);
                float h[4];
                #pragma unroll
                for (int j = 0; j < 4; ++j)
                    h[j] = fmaf(bf2f((short)hv.us[j]), scs[c4 + j], shs[c4 + j]);
                *(u64*)(&sHP[r * HP_STR + c4]) =
                    pack4bf(h[0] * bf2f((short)gv.us[0]), h[1] * bf2f((short)gv.us[1]),
                            h[2] * bf2f((short)gv.us[2]), h[3] * bf2f((short)gv.us[3]));
                if ((c4 >> 5) == ng) {
                    *(f32x4*)(&out_hs[((size_t)(m0 + r) * Tt + (t - 1)) * Hh + c4]) =
                        (f32x4){h[0], h[1], h[2], h[3]};
                }
                if (r == ng) {
                    #pragma unroll
                    for (int j = 0; j < 4; ++j) {
                        p0 = fmaf(h[j], sWhy[2 * (c4 + j)], p0);
                        p1 = fmaf(h[j], sWhy[2 * (c4 + j) + 1], p1);
                    }
                }
            }
            #pragma unroll
            for (int s = 1; s < 64; s <<= 1) { p0 += __shfl_xor(p0, s); p1 += __shfl_xor(p1, s); }
            if (lane == 0) { ysred[2 * w] = p0; ysred[2 * w + 1] = p1; }
            __syncthreads();
            if (tid == 0) {
                float q0 = 0.f, q1 = 0.f;
                #pragma unroll
                for (int i = 0; i < 16; ++i) { q0 += ysred[2 * i]; q1 += ysred[2 * i + 1]; }
                out_ys[((size_t)(m0 + ng) * Tt + (t - 1)) * Oo + 0] = softplusf_(q0 + bhy0);
                out_ys[((size_t)(m0 + ng) * Tt + (t - 1)) * Oo + 1] = softplusf_(q1 + bhy1);
            }
        } else {
            #pragma unroll
            for (int i = 0; i < 2; ++i) {
                const int idx = tid + i * 1024;
                const int r = idx >> 7, c4 = (idx & 127) * 4;
                *(u64*)(&sHP[r * HP_STR + c4]) = 0ull;
            }
            __syncthreads();
        }

        // ======= Phase A rest: hp-part MFMAs + scratch dump ================
        if (kh == 1) {
            #pragma unroll
            for (int s = 2; s < 6; ++s)
                accA = mfma_bf16(wA[s],
                    *(const short8*)(&sHP[c * HP_STR + 32 * (s - 2) + 8 * g]), accA);
        } else if (kh == 2) {
            #pragma unroll
            for (int s = 0; s < 6; ++s)
                accA = mfma_bf16(wA[s],
                    *(const short8*)(&sHP[c * HP_STR + 128 + 32 * s + 8 * g]), accA);
        } else if (kh == 3) {
            #pragma unroll
            for (int s = 0; s < 6; ++s)
                accA = mfma_bf16(wA[s],
                    *(const short8*)(&sHP[c * HP_STR + 320 + 32 * s + 8 * g]), accA);
        }
        {
            float* sp = scratch + tid * 4;
            sp[0] = accA[0]; sp[1] = accA[1]; sp[2] = accA[2]; sp[3] = accA[3];
        }
        __syncthreads();
        // ---- flat A epilogue: 256 threads x 4 cols ----
        if (tid < 256) {
            const int ct = tid >> 6, rem = tid & 63;
            const int row = rem & 15, q4 = rem >> 4;
            const int lidx = row + 16 * q4;
            float v4[4];
            #pragma unroll
            for (int j = 0; j < 4; ++j) {
                float s = 0.f;
                #pragma unroll
                for (int k2 = 0; k2 < 4; ++k2)
                    s += scratch[((k2 * 4 + ct) * 64 + lidx) * 4 + j];
                v4[j] = s;
            }
            if (ct < 2) {
                #pragma unroll
                for (int j = 0; j < 4; ++j) {
                    const int lc = ct * 16 + q4 * 4 + j;
                    sZ[lc * 17 + row] = sigmoidf_(v4[j] + bias1[ng * 32 + lc]);
                }
            } else {
                const int nn0 = ng * 32 + (ct - 2) * 16 + q4 * 4;
                float rv[4];
                #pragma unroll
                for (int j = 0; j < 4; ++j) {
                    const float v = sigmoidf_(v4[j] + bias1[512 + nn0 + j]);
                    rv[j] = v * bf2f(sHP[row * HP_STR + nn0 + j]);
                }
                AST_F((u64*)(rhG + ((size_t)(m0 + row) * Hh + nn0)),
                      pack4bf(rv[0], rv[1], rv[2], rv[3]));
            }
        }
        // ---- bar1: sub-barrier over same-mt group (gates rhG) ----
        __syncthreads();
        if (tid == 0) AST_F(&f1[bid * 16], t + 1);
        // window duties: prefetch Ghb(t+1); zero stats parity (t+1)%3
        if (t + 1 < Tt) {
            #pragma unroll
            for (int i = 0; i < 2; ++i) {
                const int idx = tid + i * 1024;
                const int r = idx >> 7, c4 = (idx & 127) * 4;
                const u64 v = *(const u64*)(Ghb + ((size_t)(t + 1) * Bb + m0 + r) * Hh + c4);
                *(u64*)(&sGH[r * GH_STR + c4]) = v;
            }
        }
        if (tid < 4) AST_F(&PstSum[((t + 1) % 3) * 1024 + bid * 4 + tid], 0.f);
        if (tid < 16) {
            while (__hip_atomic_load(&f1[(mt + 16 * tid) * 16],
                                     __ATOMIC_RELAXED, __HIP_MEMORY_SCOPE_AGENT) < t + 1)
                __builtin_amdgcn_s_sleep(1);
        }
        __syncthreads();

        // ======= Phase B rest: RH part (direct IC) + scratch dump ==========
        if (kq == 2) {
            accB = mfma_bf16(wB[2],
                ald16(rhG + (size_t)(m0 + c) * Hh + 8 * g), accB);
        } else if (kq >= 3) {
            #pragma unroll
            for (int s = 0; s < 3; ++s)
                accB = mfma_bf16(wB[s],
                    ald16(rhG + (size_t)(m0 + c) * Hh + (kq * 96 + 32 * s - 256) + 8 * g), accB);
        }
        {
            float* sp = scratch + tid * 4;
            sp[0] = accB[0]; sp[1] = accB[1]; sp[2] = accB[2]; sp[3] = accB[3];
        }
        __syncthreads();
        // ---- flat B epilogue: 128 threads x 4 cols ----
        if (tid < 128) {
            const int row = tid & 15, q8 = tid >> 4;
            const int c2 = q8 >> 2, q4 = q8 & 3;
            const int lidx = row + 16 * q4;
            float hr4[4], sp4[4], sq4[4];
            #pragma unroll
            for (int j = 0; j < 4; ++j) {
                float s = 0.f;
                #pragma unroll
                for (int k2 = 0; k2 < 8; ++k2)
                    s += scratch[((k2 * 2 + c2) * 64 + lidx) * 4 + j];
                const int lc = c2 * 16 + q4 * 4 + j;
                const int col = ng * 32 + lc;
                const float pre = s + b_h[col];
                const float z = sZ[lc * 17 + row];
                const float hp = bf2f(sHP[row * HP_STR + col]);
                const float hr = (1.f - z) * hp + z * tanhf(pre);
                hr4[j] = hr; sp4[j] = hr; sq4[j] = hr * hr;
            }
            #pragma unroll
            for (int j = 0; j < 4; ++j) {
                #pragma unroll
                for (int s = 1; s < 16; s <<= 1) {
                    sp4[j] += __shfl_xor(sp4[j], s);
                    sq4[j] += __shfl_xor(sq4[j], s);
                }
            }
            const int cb = ng * 32 + c2 * 16 + q4 * 4;
            AST_F((u64*)(HrawG + (size_t)(m0 + row) * Hh + cb),
                  pack4bf(hr4[0], hr4[1], hr4[2], hr4[3]));
            if (row == 0) {
                const int pC = t % 3;
                #pragma unroll
                for (int j = 0; j < 4; ++j) {
                    AADD_F(&PstSum[pC * 1024 + cb + j], sp4[j]);
                    AADD_F(&PstSum[pC * 1024 + 512 + cb + j], sq4[j]);
                }
            }
        }
        // ---- bar2: global barrier (gates stats + HrawG) ----
        __syncthreads();
        if (tid == 0) AST_F(&f2[bid * 16], t + 1);
        if (t + 1 < Tt && tid < 512) {
            const int r = tid >> 5, cu = tid & 31;
            const short* src = (cu < 16)
                ? (Xe + ((size_t)(t + 1) * Bb + m0 + r) * Ii + 8 * cu)
                : (Ma + ((size_t)(t + 1) * Bb + m0 + r) * Ii + 8 * (cu - 16));
            *(short8*)(&sXM[r * XM_STR + 8 * cu]) = *(const short8*)src;
        }
        if (tid < 256) {
            while (__hip_atomic_load(&f2[tid * 16],
                                     __ATOMIC_RELAXED, __HIP_MEMORY_SCOPE_AGENT) < t + 1)
                __builtin_amdgcn_s_sleep(1);
        }
        __syncthreads();
    }

    // ================= tail: BN + outputs for t = Tt-1 =====================
    {
        const int pR = (Tt - 1) % 3;
        if (tid < 512) {
            const float s1 = ALD_F(&PstSum[pR * 1024 + tid]);
            const float s2 = ALD_F(&PstSum[pR * 1024 + 512 + tid]);
            const float mu = s1 * (1.f / 256.f);
            const float var = fmaxf(s2 * (1.f / 256.f) - mu * mu, 0.f);
            const float sc = bn_g[tid] * rsqrtf(var + EPS_BN);
            scs[tid] = sc; shs[tid] = bn_b[tid] - mu * sc;
        }
        __syncthreads();
        float p0 = 0.f, p1 = 0.f;
        #pragma unroll
        for (int i = 0; i < 2; ++i) {
            const int idx = tid + i * 1024;
            const int r = idx >> 7, c4 = (idx & 127) * 4;
            union { u64 u; unsigned short us[4]; } hv;
            hv.u = ALD_F((const u64*)(HrawG + (size_t)(m0 + r) * Hh + c4));
            float h[4];
            #pragma unroll
            for (int j = 0; j < 4; ++j)
                h[j] = fmaf(bf2f((short)hv.us[j]), scs[c4 + j], shs[c4 + j]);
            if ((c4 >> 5) == ng) {
                *(f32x4*)(&out_hs[((size_t)(m0 + r) * Tt + (Tt - 1)) * Hh + c4]) =
                    (f32x4){h[0], h[1], h[2], h[3]};
            }
            if (r == ng) {
                #pragma unroll
                for (int j = 0; j < 4; ++j) {
                    p0 = fmaf(h[j], sWhy[2 * (c4 + j)], p0);
                    p1 = fmaf(h[j], sWhy[2 * (c4 + j) + 1], p1);
                }
            }
        }
        #pragma unroll
        for (int s = 1; s < 64; s <<= 1) { p0 += __shfl_xor(p0, s); p1 += __shfl_xor(p1, s); }
        if (lane == 0) { ysred[2 * w] = p0; ysred[2 * w + 1] = p1; }
        __syncthreads();
        if (tid == 0) {
            float q0 = 0.f, q1 = 0.f;
            #pragma unroll
            for (int i = 0; i < 16; ++i) { q0 += ysred[2 * i]; q1 += ysred[2 * i + 1]; }
            out_ys[((size_t)(m0 + ng) * Tt + (Tt - 1)) * Oo + 0] = softplusf_(q0 + bhy0);
            out_ys[((size_t)(m0 + ng) * Tt + (Tt - 1)) * Oo + 1] = softplusf_(q1 + bhy1);
        }
    }
}

// ---------------------------------------------------------------------------
extern "C" void kernel_launch(void* const* d_in, const int* in_sizes, int n_in,
                              void* d_out, int out_size, void* d_ws, size_t ws_size,
                              hipStream_t stream)
{
    const float* input  = (const float*)d_in[0];
    const float* xmean  = (const float*)d_in[1];
    const float* W_dg_x = (const float*)d_in[2];
    const float* b_dg_x = (const float*)d_in[3];
    const float* W_dg_h = (const float*)d_in[4];
    const float* b_dg_h = (const float*)d_in[5];
    const float* W_xz   = (const float*)d_in[6];
    const float* W_hz   = (const float*)d_in[7];
    const float* W_mz   = (const float*)d_in[8];
    const float* b_z    = (const float*)d_in[9];
    const float* W_xr   = (const float*)d_in[10];
    const float* W_hr   = (const float*)d_in[11];
    const float* W_mr   = (const float*)d_in[12];
    const float* b_r    = (const float*)d_in[13];
    const float* W_xh   = (const float*)d_in[14];
    const float* W_hh   = (const float*)d_in[15];
    const float* W_mh   = (const float*)d_in[16];
    const float* b_h    = (const float*)d_in[17];
    const float* W_hy   = (const float*)d_in[18];
    const float* b_hy   = (const float*)d_in[19];
    const float* bn_g   = (const float*)d_in[20];
    const float* bn_b   = (const float*)d_in[21];

    float* out_ys = (float*)d_out;
    float* out_hs = out_ys + (size_t)Bb * Tt * Oo;

    char* p = (char*)d_ws;
    float* Xall = (float*)p;            p += (size_t)TBr * Ii * 4;
    short* Mall = (short*)p;            p += (size_t)TBr * Ii * 2;
    short* Dall = (short*)p;            p += (size_t)TBr * Ii * 2;
    short* Gxb  = (short*)p;            p += (size_t)TBr * Ii * 2;
    short* Ghb  = (short*)p;            p += (size_t)TBr * Hh * 2;
    short* Xe   = (short*)p;            p += (size_t)TBr * Ii * 2;
    short* Wc1T = (short*)p;            p += (size_t)1024 * 768 * 2;
    short* Wc2T = (short*)p;            p += (size_t)512 * 768 * 2;
    short* WdgxT= (short*)p;            p += (size_t)128 * 128 * 2;
    short* WdghT= (short*)p;            p += (size_t)512 * 128 * 2;
    float* bias1= (float*)p;            p += 1024 * 4;
    short* rhG  = (short*)p;            p += (size_t)Bb * Hh * 2;
    short* HrawG= (short*)p;            p += (size_t)Bb * Hh * 2;
    float* PstSum=(float*)p;            p += 3 * 1024 * 4;
    int*   f1   = (int*)p;              p += 256 * 16 * 4;
    int*   f2   = (int*)p;              p += 256 * 16 * 4;

    hipMemsetAsync(f1, 0, 256 * 16 * 4, stream);
    hipMemsetAsync(f2, 0, 256 * 16 * 4, stream);
    hipMemsetAsync(PstSum, 0, 3 * 1024 * 4, stream);

    repack_kernel<<<dim3(Tt / 32, Ii / 32, Bb * 3), dim3(32, 32), 0, stream>>>(input, Xall, Mall, Dall);

    {
        const int total = 1024 * 768 + 512 * 768 + 128 * 128 + 512 * 128 + 1024;
        pack_weights_kernel<<<(total + 255) / 256, 256, 0, stream>>>(
            W_dg_x, W_dg_h,
            W_xz, W_hz, W_mz, b_z,
            W_xr, W_hr, W_mr, b_r,
            W_xh, W_hh, W_mh,
            Wc1T, Wc2T, WdgxT, WdghT, bias1);
    }

    gdecay_kernel<<<dim3(TBr / 32, Ii / 64), 64, 0, stream>>>(Dall, WdgxT, b_dg_x, Gxb, Ii);
    gdecay_kernel<<<dim3(TBr / 32, Hh / 64), 64, 0, stream>>>(Dall, WdghT, b_dg_h, Ghb, Hh);

    xeff_scan_kernel<<<(Bb * Ii) / 256, 256, 0, stream>>>(Xall, Mall, Gxb, xmean, Xe);

    grud_persistent<<<256, 1024, 0, stream>>>(
        Xe, Mall, Ghb, Wc1T, Wc2T, bias1, b_h, bn_g, bn_b,
        W_hy, b_hy, rhG, HrawG, PstSum, f1, f2, out_hs, out_ys);
}

// Round 10
// 2721.226 us; speedup vs baseline: 1.0619x; 1.0619x over previous
//
#include <hip/hip_runtime.h>
#include <math.h>

#define Bb 256
#define Ii 128
#define Tt 256
#define Hh 512
#define Oo 2
#define TBr (Tt*Bb)
#define EPS_BN 1e-5f

typedef __attribute__((ext_vector_type(8))) short short8;
typedef __attribute__((ext_vector_type(8))) __bf16 bf16x8;
typedef __attribute__((ext_vector_type(4))) float f32x4;
typedef unsigned long long u64;

__device__ __forceinline__ f32x4 mfma_bf16(short8 a, short8 b, f32x4 c) {
    return __builtin_amdgcn_mfma_f32_16x16x32_bf16(
        __builtin_bit_cast(bf16x8, a), __builtin_bit_cast(bf16x8, b), c, 0, 0, 0);
}
__device__ __forceinline__ short f2bf(float f) {
    union { float f; unsigned u; } v; v.f = f;
    unsigned r = (v.u + 0x7FFFu + ((v.u >> 16) & 1u)) >> 16;
    return (short)r;
}
__device__ __forceinline__ float bf2f(short s) {
    union { unsigned u; float f; } v; v.u = ((unsigned)(unsigned short)s) << 16;
    return v.f;
}
__device__ __forceinline__ float sigmoidf_(float x) { return 1.f / (1.f + expf(-x)); }
__device__ __forceinline__ float softplusf_(float x) { return fmaxf(x, 0.f) + log1pf(expf(-fabsf(x))); }

#define ALD_F(p)  __hip_atomic_load((p),  __ATOMIC_RELAXED, __HIP_MEMORY_SCOPE_AGENT)
#define AST_F(p,v) __hip_atomic_store((p), (v), __ATOMIC_RELAXED, __HIP_MEMORY_SCOPE_AGENT)
#define AADD_F(p,v) (void)__hip_atomic_fetch_add((p), (v), __ATOMIC_RELAXED, __HIP_MEMORY_SCOPE_AGENT)

__device__ __forceinline__ short8 ald16(const short* p) {
    union { u64 u[2]; short8 s; } v;
    v.u[0] = ALD_F((const u64*)p);
    v.u[1] = ALD_F((const u64*)(p + 4));
    return v.s;
}
__device__ __forceinline__ u64 pack4bf(float a, float b, float c_, float d) {
    return (u64)(unsigned short)f2bf(a)
         | ((u64)(unsigned short)f2bf(b) << 16)
         | ((u64)(unsigned short)f2bf(c_) << 32)
         | ((u64)(unsigned short)f2bf(d) << 48);
}

// ---------------------------------------------------------------------------
// repack: input [B,3,I,T] fp32 -> time-major X fp32 [T,B,I], M bf16, D bf16
// ---------------------------------------------------------------------------
__global__ __launch_bounds__(1024) void repack_kernel(const float* __restrict__ in,
                                                      float* __restrict__ Xall,
                                                      short* __restrict__ Mall,
                                                      short* __restrict__ Dall)
{
    __shared__ float tile[32][33];
    const int bz = blockIdx.z;
    const int b = bz / 3, cch = bz % 3;
    const int t0 = blockIdx.x * 32, i0 = blockIdx.y * 32;
    const int tx = threadIdx.x, ty = threadIdx.y;
    const float* src = in + ((size_t)b * 3 + cch) * (size_t)Ii * Tt;
    tile[ty][tx] = src[(size_t)(i0 + ty) * Tt + t0 + tx];
    __syncthreads();
    const float v = tile[tx][ty];
    const size_t off = ((size_t)(t0 + ty) * Bb + b) * Ii + i0 + tx;
    if (cch == 0)      Xall[off] = v;
    else if (cch == 1) Mall[off] = f2bf(v);
    else               Dall[off] = f2bf(v);
}

// ---------------------------------------------------------------------------
// pack weights -> bf16 transposed (n-major, k rows) for MFMA fragments
// ---------------------------------------------------------------------------
__global__ __launch_bounds__(256) void pack_weights_kernel(
    const float* __restrict__ W_dg_x, const float* __restrict__ W_dg_h,
    const float* __restrict__ W_xz, const float* __restrict__ W_hz, const float* __restrict__ W_mz, const float* __restrict__ b_z,
    const float* __restrict__ W_xr, const float* __restrict__ W_hr, const float* __restrict__ W_mr, const float* __restrict__ b_r,
    const float* __restrict__ W_xh, const float* __restrict__ W_hh, const float* __restrict__ W_mh,
    short* __restrict__ Wc1T, short* __restrict__ Wc2T,
    short* __restrict__ WdgxT, short* __restrict__ WdghT, float* __restrict__ bias1)
{
    const int idx = blockIdx.x * blockDim.x + threadIdx.x;
    const int n1 = 1024 * 768, n2 = 512 * 768, n3 = 128 * 128, n4 = 512 * 128;
    if (idx < n1) {
        const int n = idx / 768, k = idx % 768;
        const int col = (n < Hh) ? n : (n - Hh);
        const float* Wx = (n < Hh) ? W_xz : W_xr;
        const float* Wm = (n < Hh) ? W_mz : W_mr;
        const float* Wh = (n < Hh) ? W_hz : W_hr;
        float v;
        if (k < Ii)        v = Wx[(size_t)k * Hh + col];
        else if (k < 2*Ii) v = Wm[(size_t)(k - Ii) * Hh + col];
        else               v = Wh[(size_t)(k - 2*Ii) * Hh + col];
        Wc1T[idx] = f2bf(v);
    } else if (idx < n1 + n2) {
        const int j = idx - n1;
        const int n = j / 768, k = j % 768;
        float v;
        if (k < Ii)        v = W_xh[(size_t)k * Hh + n];
        else if (k < 2*Ii) v = W_mh[(size_t)(k - Ii) * Hh + n];
        else               v = W_hh[(size_t)(k - 2*Ii) * Hh + n];
        Wc2T[j] = f2bf(v);
    } else if (idx < n1 + n2 + n3) {
        const int j = idx - n1 - n2;
        const int n = j >> 7, k = j & 127;
        WdgxT[j] = f2bf(W_dg_x[(size_t)k * Ii + n]);
    } else if (idx < n1 + n2 + n3 + n4) {
        const int j = idx - n1 - n2 - n3;
        const int n = j >> 7, k = j & 127;
        WdghT[j] = f2bf(W_dg_h[(size_t)k * Hh + n]);
    } else if (idx < n1 + n2 + n3 + n4 + 1024) {
        const int n = idx - n1 - n2 - n3 - n4;
        bias1[n] = (n < Hh) ? b_z[n] : b_r[n - Hh];
    }
}

// ---------------------------------------------------------------------------
// gdecay: C = bf16(exp(-relu(A @ B + bias)))
// ---------------------------------------------------------------------------
__global__ __launch_bounds__(64) void gdecay_kernel(const short* __restrict__ A,
                                                    const short* __restrict__ BT,
                                                    const float* __restrict__ bias,
                                                    short* __restrict__ C, int N)
{
    const int lane = threadIdx.x;
    const int c = lane & 15, g = lane >> 4;
    const int m0 = blockIdx.x * 32, n0 = blockIdx.y * 64;
    const short* a0 = A + (size_t)(m0 + c) * Ii + 8 * g;
    const short* a1 = a0 + (size_t)16 * Ii;
    const short* bw = BT + (size_t)(n0 + c) * Ii + 8 * g;
    f32x4 acc[2][4];
    #pragma unroll
    for (int i = 0; i < 2; ++i)
        #pragma unroll
        for (int f = 0; f < 4; ++f) acc[i][f] = (f32x4){0.f, 0.f, 0.f, 0.f};
    #pragma unroll
    for (int k0 = 0; k0 < 128; k0 += 32) {
        const short8 av0 = *(const short8*)(a0 + k0);
        const short8 av1 = *(const short8*)(a1 + k0);
        #pragma unroll
        for (int fn = 0; fn < 4; ++fn) {
            const short8 bv = *(const short8*)(bw + (size_t)fn * 16 * Ii + k0);
            acc[0][fn] = mfma_bf16(av0, bv, acc[0][fn]);
            acc[1][fn] = mfma_bf16(av1, bv, acc[1][fn]);
        }
    }
    #pragma unroll
    for (int fn = 0; fn < 4; ++fn) {
        const int n = n0 + fn * 16 + c;
        const float bs = bias[n];
        #pragma unroll
        for (int fm = 0; fm < 2; ++fm) {
            #pragma unroll
            for (int j = 0; j < 4; ++j) {
                const int m = m0 + fm * 16 + 4 * g + j;
                const float v = expf(-fmaxf(acc[fm][fn][j] + bs, 0.f));
                C[(size_t)m * N + n] = f2bf(v);
            }
        }
    }
}

// ---------------------------------------------------------------------------
// x_last scan + x_eff -> Xe bf16 [T,B,I]
// ---------------------------------------------------------------------------
__global__ __launch_bounds__(256) void xeff_scan_kernel(const float* __restrict__ Xall,
                                                        const short* __restrict__ Mall,
                                                        const short* __restrict__ Gx,
                                                        const float* __restrict__ xmean_p,
                                                        short* __restrict__ Xe)
{
    const int bi = blockIdx.x * blockDim.x + threadIdx.x;
    if (bi >= Bb * Ii) return;
    const float xm = xmean_p[0];
    float xl = 0.f;
    for (int t = 0; t < Tt; ++t) {
        const size_t off = (size_t)t * Bb * Ii + bi;
        const float x = Xall[off];
        const float m = bf2f(Mall[off]);
        const float gx = bf2f(Gx[off]);
        if (m > 0.f) xl = x;
        Xe[off] = f2bf(m * x + (1.f - m) * (gx * xl + (1.f - gx) * xm));
    }
}

// ---------------------------------------------------------------------------
// persistent: 256 blocks x 512 thr. block (mt = bid&15, ng = bid>>4):
// rows m0=mt*16..+16; z cols ng*32; r cols 512+ng*32; htilde cols ng*32.
// bar1: per-WAVE fine-grained waits on the specific peers whose rh cols the
// wave consumes (kq1: ng'0-3, kq2: 4-9, kq3: 10-15; kq0 none).
// bar2: global flag barrier, polled by ONE wave (64 thr x 4 flags).
// ---------------------------------------------------------------------------
#define XM_STR 264
#define HP_STR 520
#define GH_STR 520

__global__ __launch_bounds__(512, 1) void grud_persistent(
    const short* __restrict__ Xe, const short* __restrict__ Ma,
    const short* __restrict__ Ghb,
    const short* __restrict__ Wc1T, const short* __restrict__ Wc2T,
    const float* __restrict__ bias1, const float* __restrict__ b_h,
    const float* __restrict__ bn_g, const float* __restrict__ bn_b,
    const float* __restrict__ Why, const float* __restrict__ bhy,
    short* __restrict__ rhG,          // [256][512] bf16  (atomic-only)
    short* __restrict__ HrawG,        // [256][512] bf16  (atomic-only)
    float* __restrict__ PstSum,       // [3][1024] f32    (atomic-only)
    int* __restrict__ f1,             // [256][16] int    (atomic-only)
    int* __restrict__ f2,             // [256][16] int    (atomic-only)
    float* __restrict__ out_hs, float* __restrict__ out_ys)
{
    const int bid = blockIdx.x, tid = threadIdx.x;
    const int w = tid >> 6, lane = tid & 63, c = lane & 15, g = lane >> 4;
    const int mt = bid & 15, ng = bid >> 4;
    const int m0 = mt * 16;

    __shared__ short sXM[16 * XM_STR];       // 8.4 KB
    __shared__ short sHP[16 * HP_STR];       // 16.6 KB
    __shared__ short sGH[16 * GH_STR];       // 16.6 KB
    __shared__ float sZ[32 * 17];            // 2.2 KB  [localcol][row]
    __shared__ float scratch[1536];          // 6 KB k-split reduce
    __shared__ float sWhy[1024];             // 4 KB
    __shared__ float scs[512], shs[512];     // 4 KB
    __shared__ float ysred[16];

    sWhy[tid] = Why[tid]; sWhy[tid + 512] = Why[tid + 512];
    const float bhy0 = bhy[0], bhy1 = bhy[1];

    const int colt = w & 3, kh = w >> 2;             // phase A role
    const int colbaseA = (colt < 2) ? (ng * 32 + colt * 16)
                                    : (512 + ng * 32 + (colt - 2) * 16);
    short8 wA[12];
    {
        const short* bw = Wc1T + (size_t)(colbaseA + c) * 768 + kh * 384 + 8 * g;
        #pragma unroll
        for (int s = 0; s < 12; ++s) wA[s] = *(const short8*)(bw + 32 * s);
    }
    const int colt2 = w & 1, kq = w >> 1;            // phase B role
    const int colbaseB = ng * 32 + colt2 * 16;
    short8 wB[6];
    {
        const short* bw = Wc2T + (size_t)(colbaseB + c) * 768 + kq * 192 + 8 * g;
        #pragma unroll
        for (int s = 0; s < 6; ++s) wB[s] = *(const short8*)(bw + 32 * s);
    }
    // per-wave peer set for fine-grained rh wait
    // kq==1 -> ng' 0..3 ; kq==2 -> ng' 4..9 ; kq==3 -> ng' 10..15
    const int npeer = (kq == 1) ? 4 : (kq >= 2 ? 6 : 0);
    const int peer0 = (kq == 1) ? 0 : (kq == 2 ? 4 : 10);
    const int peerflag = (lane < npeer) ? ((mt + 16 * (peer0 + lane)) * 16) : -1;

    // ---- stage [Xe|Ma] for t=0 ----
    {
        const int r = tid >> 5, cu = tid & 31;
        const short* src = (cu < 16)
            ? (Xe + ((size_t)(m0 + r)) * Ii + 8 * cu)
            : (Ma + ((size_t)(m0 + r)) * Ii + 8 * (cu - 16));
        *(short8*)(&sXM[r * XM_STR + 8 * cu]) = *(const short8*)src;
    }
    __syncthreads();

    for (int t = 0; t < Tt; ++t) {
        // ======= loop-top: [Xe|Ma]-only MFMA partials ======================
        f32x4 accA = (f32x4){0.f, 0.f, 0.f, 0.f};
        f32x4 accB = (f32x4){0.f, 0.f, 0.f, 0.f};
        if (kh == 0) {
            #pragma unroll
            for (int s = 0; s < 8; ++s)
                accA = mfma_bf16(wA[s],
                    *(const short8*)(&sXM[c * XM_STR + 32 * s + 8 * g]), accA);
        }
        #pragma unroll
        for (int s = 0; s < 6; ++s) {
            const int k = kq * 192 + 32 * s;
            if (k < 256)
                accB = mfma_bf16(wB[s],
                    *(const short8*)(&sXM[c * XM_STR + k + 8 * g]), accB);
        }

        // ======= stage: BN(t-1) scale/shift, hp, out_hs(t-1), ys(t-1) ======
        if (t > 0) {
            const int pR = (t + 2) % 3;               // (t-1) mod 3
            {
                const float s1 = ALD_F(&PstSum[pR * 1024 + tid]);
                const float s2 = ALD_F(&PstSum[pR * 1024 + 512 + tid]);
                const float mu = s1 * (1.f / 256.f);
                const float var = fmaxf(s2 * (1.f / 256.f) - mu * mu, 0.f);
                const float sc = bn_g[tid] * rsqrtf(var + EPS_BN);
                scs[tid] = sc; shs[tid] = bn_b[tid] - mu * sc;
            }
            __syncthreads();
            float p0 = 0.f, p1 = 0.f;
            #pragma unroll
            for (int i = 0; i < 4; ++i) {
                const int idx = tid + i * 512;        // u64 granule in 16x128
                const int r = idx >> 7, c4 = (idx & 127) * 4;
                union { u64 u; unsigned short us[4]; } hv, gv;
                hv.u = ALD_F((const u64*)(HrawG + (size_t)(m0 + r) * Hh + c4));
                gv.u = *(const u64*)(&sGH[r * GH_STR + c4]);
                float h[4];
                #pragma unroll
                for (int j = 0; j < 4; ++j)
                    h[j] = fmaf(bf2f((short)hv.us[j]), scs[c4 + j], shs[c4 + j]);
                *(u64*)(&sHP[r * HP_STR + c4]) =
                    pack4bf(h[0] * bf2f((short)gv.us[0]), h[1] * bf2f((short)gv.us[1]),
                            h[2] * bf2f((short)gv.us[2]), h[3] * bf2f((short)gv.us[3]));
                if ((c4 >> 5) == ng) {
                    *(f32x4*)(&out_hs[((size_t)(m0 + r) * Tt + (t - 1)) * Hh + c4]) =
                        (f32x4){h[0], h[1], h[2], h[3]};
                }
                if (r == ng) {
                    #pragma unroll
                    for (int j = 0; j < 4; ++j) {
                        p0 = fmaf(h[j], sWhy[2 * (c4 + j)], p0);
                        p1 = fmaf(h[j], sWhy[2 * (c4 + j) + 1], p1);
                    }
                }
            }
            #pragma unroll
            for (int s = 1; s < 64; s <<= 1) { p0 += __shfl_xor(p0, s); p1 += __shfl_xor(p1, s); }
            if (lane == 0) { ysred[2 * w] = p0; ysred[2 * w + 1] = p1; }
            __syncthreads();
            if (tid == 0) {
                float q0 = 0.f, q1 = 0.f;
                #pragma unroll
                for (int i = 0; i < 8; ++i) { q0 += ysred[2 * i]; q1 += ysred[2 * i + 1]; }
                out_ys[((size_t)(m0 + ng) * Tt + (t - 1)) * Oo + 0] = softplusf_(q0 + bhy0);
                out_ys[((size_t)(m0 + ng) * Tt + (t - 1)) * Oo + 1] = softplusf_(q1 + bhy1);
            }
        } else {
            #pragma unroll
            for (int i = 0; i < 4; ++i) {
                const int idx = tid + i * 512;
                const int r = idx >> 7, c4 = (idx & 127) * 4;
                *(u64*)(&sHP[r * HP_STR + c4]) = 0ull;
            }
            __syncthreads();
        }

        // ======= Phase A rest: hp part + k-split reduce + epilogue =========
        if (kh == 0) {
            #pragma unroll
            for (int s = 8; s < 12; ++s)
                accA = mfma_bf16(wA[s],
                    *(const short8*)(&sHP[c * HP_STR + (32 * s - 256) + 8 * g]), accA);
        } else {
            #pragma unroll
            for (int s = 0; s < 12; ++s)
                accA = mfma_bf16(wA[s],
                    *(const short8*)(&sHP[c * HP_STR + 128 + 32 * s + 8 * g]), accA);
        }
        if (kh == 1) {
            float* sp = scratch + (colt * 64 + lane) * 4;
            sp[0] = accA[0]; sp[1] = accA[1]; sp[2] = accA[2]; sp[3] = accA[3];
        }
        __syncthreads();
        if (kh == 0) {
            const float* sp = scratch + (colt * 64 + lane) * 4;
            accA[0] += sp[0]; accA[1] += sp[1]; accA[2] += sp[2]; accA[3] += sp[3];
            if (colt < 2) {
                #pragma unroll
                for (int j = 0; j < 4; ++j) {
                    const int lc = colt * 16 + 4 * g + j;
                    const float v = sigmoidf_(accA[j] + bias1[ng * 32 + lc]);
                    sZ[lc * 17 + c] = v;
                }
            } else {
                const int nn0 = ng * 32 + (colt - 2) * 16 + 4 * g;
                float rv[4];
                #pragma unroll
                for (int j = 0; j < 4; ++j) {
                    const float v = sigmoidf_(accA[j] + bias1[512 + nn0 + j]);
                    rv[j] = v * bf2f(sHP[c * HP_STR + nn0 + j]);
                }
                AST_F((u64*)(rhG + ((size_t)(m0 + c) * Hh + nn0)),
                      pack4bf(rv[0], rv[1], rv[2], rv[3]));
            }
        }
        // ---- bar1 arrive (no global wait; waves wait fine-grained below) --
        __syncthreads();                     // drains rhG stores (vmcnt)
        if (tid == 0) AST_F(&f1[bid * 16], t + 1);
        // window duties: prefetch Ghb(t+1); zero stats parity (t+1)%3
        if (t + 1 < Tt) {
            #pragma unroll
            for (int i = 0; i < 4; ++i) {
                const int idx = tid + i * 512;
                const int r = idx >> 7, c4 = (idx & 127) * 4;
                const u64 v = *(const u64*)(Ghb + ((size_t)(t + 1) * Bb + m0 + r) * Hh + c4);
                *(u64*)(&sGH[r * GH_STR + c4]) = v;
            }
        }
        if (tid < 4) AST_F(&PstSum[((t + 1) % 3) * 1024 + bid * 4 + tid], 0.f);

        // ======= Phase B rest: per-wave peer wait + rh MFMAs (direct IC) ===
        if (npeer > 0) {
            for (;;) {
                const int v = (lane < npeer)
                    ? __hip_atomic_load(&f1[peerflag], __ATOMIC_RELAXED, __HIP_MEMORY_SCOPE_AGENT)
                    : 0x7fffffff;
                if (__all(v >= t + 1)) break;
                __builtin_amdgcn_s_sleep(1);
            }
            asm volatile("" ::: "memory");
        }
        #pragma unroll
        for (int s = 0; s < 6; ++s) {
            const int k = kq * 192 + 32 * s;
            if (k >= 256)
                accB = mfma_bf16(wB[s],
                    ald16(rhG + (size_t)(m0 + c) * Hh + (k - 256) + 8 * g), accB);
        }
        if (kq > 0) {
            float* sp = scratch + ((colt2 * 3 + kq - 1) * 64 + lane) * 4;
            sp[0] = accB[0]; sp[1] = accB[1]; sp[2] = accB[2]; sp[3] = accB[3];
        }
        __syncthreads();
        if (kq == 0) {
            #pragma unroll
            for (int qq = 0; qq < 3; ++qq) {
                const float* sp = scratch + ((colt2 * 3 + qq) * 64 + lane) * 4;
                accB[0] += sp[0]; accB[1] += sp[1]; accB[2] += sp[2]; accB[3] += sp[3];
            }
            const int pC = t % 3;
            float hr4[4];
            #pragma unroll
            for (int j = 0; j < 4; ++j) {
                const int lc = colt2 * 16 + 4 * g + j;
                const int col = ng * 32 + lc;
                const float pre = accB[j] + b_h[col];
                const float z = sZ[lc * 17 + c];
                const float hp = bf2f(sHP[c * HP_STR + col]);
                const float hr = (1.f - z) * hp + z * tanhf(pre);
                hr4[j] = hr;
                float sp_ = hr, sq_ = hr * hr;
                sp_ += __shfl_xor(sp_, 1); sq_ += __shfl_xor(sq_, 1);
                sp_ += __shfl_xor(sp_, 2); sq_ += __shfl_xor(sq_, 2);
                sp_ += __shfl_xor(sp_, 4); sq_ += __shfl_xor(sq_, 4);
                sp_ += __shfl_xor(sp_, 8); sq_ += __shfl_xor(sq_, 8);
                if (c == 0) {
                    AADD_F(&PstSum[pC * 1024 + col], sp_);
                    AADD_F(&PstSum[pC * 1024 + 512 + col], sq_);
                }
            }
            const int cb = ng * 32 + colt2 * 16 + 4 * g;
            AST_F((u64*)(HrawG + (size_t)(m0 + c) * Hh + cb),
                  pack4bf(hr4[0], hr4[1], hr4[2], hr4[3]));
        }
        // ---- bar2: global barrier (gates stats + HrawG), 1-wave poll ------
        __syncthreads();
        if (tid == 0) AST_F(&f2[bid * 16], t + 1);
        if (t + 1 < Tt) {
            const int r = tid >> 5, cu = tid & 31;
            const short* src = (cu < 16)
                ? (Xe + ((size_t)(t + 1) * Bb + m0 + r) * Ii + 8 * cu)
                : (Ma + ((size_t)(t + 1) * Bb + m0 + r) * Ii + 8 * (cu - 16));
            *(short8*)(&sXM[r * XM_STR + 8 * cu]) = *(const short8*)src;
        }
        if (tid < 64) {
            for (;;) {
                const int v0 = __hip_atomic_load(&f2[(tid * 4 + 0) * 16], __ATOMIC_RELAXED, __HIP_MEMORY_SCOPE_AGENT);
                const int v1 = __hip_atomic_load(&f2[(tid * 4 + 1) * 16], __ATOMIC_RELAXED, __HIP_MEMORY_SCOPE_AGENT);
                const int v2 = __hip_atomic_load(&f2[(tid * 4 + 2) * 16], __ATOMIC_RELAXED, __HIP_MEMORY_SCOPE_AGENT);
                const int v3 = __hip_atomic_load(&f2[(tid * 4 + 3) * 16], __ATOMIC_RELAXED, __HIP_MEMORY_SCOPE_AGENT);
                int mn = v0 < v1 ? v0 : v1;
                mn = mn < v2 ? mn : v2;
                mn = mn < v3 ? mn : v3;
                if (__all(mn >= t + 1)) break;
                __builtin_amdgcn_s_sleep(1);
            }
        }
        __syncthreads();
    }

    // ================= tail: BN + outputs for t = Tt-1 =====================
    {
        const int pR = (Tt - 1) % 3;
        {
            const float s1 = ALD_F(&PstSum[pR * 1024 + tid]);
            const float s2 = ALD_F(&PstSum[pR * 1024 + 512 + tid]);
            const float mu = s1 * (1.f / 256.f);
            const float var = fmaxf(s2 * (1.f / 256.f) - mu * mu, 0.f);
            const float sc = bn_g[tid] * rsqrtf(var + EPS_BN);
            scs[tid] = sc; shs[tid] = bn_b[tid] - mu * sc;
        }
        __syncthreads();
        float p0 = 0.f, p1 = 0.f;
        #pragma unroll
        for (int i = 0; i < 4; ++i) {
            const int idx = tid + i * 512;
            const int r = idx >> 7, c4 = (idx & 127) * 4;
            union { u64 u; unsigned short us[4]; } hv;
            hv.u = ALD_F((const u64*)(HrawG + (size_t)(m0 + r) * Hh + c4));
            float h[4];
            #pragma unroll
            for (int j = 0; j < 4; ++j)
                h[j] = fmaf(bf2f((short)hv.us[j]), scs[c4 + j], shs[c4 + j]);
            if ((c4 >> 5) == ng) {
                *(f32x4*)(&out_hs[((size_t)(m0 + r) * Tt + (Tt - 1)) * Hh + c4]) =
                    (f32x4){h[0], h[1], h[2], h[3]};
            }
            if (r == ng) {
                #pragma unroll
                for (int j = 0; j < 4; ++j) {
                    p0 = fmaf(h[j], sWhy[2 * (c4 + j)], p0);
                    p1 = fmaf(h[j], sWhy[2 * (c4 + j) + 1], p1);
                }
            }
        }
        #pragma unroll
        for (int s = 1; s < 64; s <<= 1) { p0 += __shfl_xor(p0, s); p1 += __shfl_xor(p1, s); }
        if (lane == 0) { ysred[2 * w] = p0; ysred[2 * w + 1] = p1; }
        __syncthreads();
        if (tid == 0) {
            float q0 = 0.f, q1 = 0.f;
            #pragma unroll
            for (int i = 0; i < 8; ++i) { q0 += ysred[2 * i]; q1 += ysred[2 * i + 1]; }
            out_ys[((size_t)(m0 + ng) * Tt + (Tt - 1)) * Oo + 0] = softplusf_(q0 + bhy0);
            out_ys[((size_t)(m0 + ng) * Tt + (Tt - 1)) * Oo + 1] = softplusf_(q1 + bhy1);
        }
    }
}

// ---------------------------------------------------------------------------
extern "C" void kernel_launch(void* const* d_in, const int* in_sizes, int n_in,
                              void* d_out, int out_size, void* d_ws, size_t ws_size,
                              hipStream_t stream)
{
    const float* input  = (const float*)d_in[0];
    const float* xmean  = (const float*)d_in[1];
    const float* W_dg_x = (const float*)d_in[2];
    const float* b_dg_x = (const float*)d_in[3];
    const float* W_dg_h = (const float*)d_in[4];
    const float* b_dg_h = (const float*)d_in[5];
    const float* W_xz   = (const float*)d_in[6];
    const float* W_hz   = (const float*)d_in[7];
    const float* W_mz   = (const float*)d_in[8];
    const float* b_z    = (const float*)d_in[9];
    const float* W_xr   = (const float*)d_in[10];
    const float* W_hr   = (const float*)d_in[11];
    const float* W_mr   = (const float*)d_in[12];
    const float* b_r    = (const float*)d_in[13];
    const float* W_xh   = (const float*)d_in[14];
    const float* W_hh   = (const float*)d_in[15];
    const float* W_mh   = (const float*)d_in[16];
    const float* b_h    = (const float*)d_in[17];
    const float* W_hy   = (const float*)d_in[18];
    const float* b_hy   = (const float*)d_in[19];
    const float* bn_g   = (const float*)d_in[20];
    const float* bn_b   = (const float*)d_in[21];

    float* out_ys = (float*)d_out;
    float* out_hs = out_ys + (size_t)Bb * Tt * Oo;

    char* p = (char*)d_ws;
    float* Xall = (float*)p;            p += (size_t)TBr * Ii * 4;
    short* Mall = (short*)p;            p += (size_t)TBr * Ii * 2;
    short* Dall = (short*)p;            p += (size_t)TBr * Ii * 2;
    short* Gxb  = (short*)p;            p += (size_t)TBr * Ii * 2;
    short* Ghb  = (short*)p;            p += (size_t)TBr * Hh * 2;
    short* Xe   = (short*)p;            p += (size_t)TBr * Ii * 2;
    short* Wc1T = (short*)p;            p += (size_t)1024 * 768 * 2;
    short* Wc2T = (short*)p;            p += (size_t)512 * 768 * 2;
    short* WdgxT= (short*)p;            p += (size_t)128 * 128 * 2;
    short* WdghT= (short*)p;            p += (size_t)512 * 128 * 2;
    float* bias1= (float*)p;            p += 1024 * 4;
    short* rhG  = (short*)p;            p += (size_t)Bb * Hh * 2;
    short* HrawG= (short*)p;            p += (size_t)Bb * Hh * 2;
    float* PstSum=(float*)p;            p += 3 * 1024 * 4;
    int*   f1   = (int*)p;              p += 256 * 16 * 4;
    int*   f2   = (int*)p;              p += 256 * 16 * 4;

    hipMemsetAsync(f1, 0, 256 * 16 * 4, stream);
    hipMemsetAsync(f2, 0, 256 * 16 * 4, stream);
    hipMemsetAsync(PstSum, 0, 3 * 1024 * 4, stream);

    repack_kernel<<<dim3(Tt / 32, Ii / 32, Bb * 3), dim3(32, 32), 0, stream>>>(input, Xall, Mall, Dall);

    {
        const int total = 1024 * 768 + 512 * 768 + 128 * 128 + 512 * 128 + 1024;
        pack_weights_kernel<<<(total + 255) / 256, 256, 0, stream>>>(
            W_dg_x, W_dg_h,
            W_xz, W_hz, W_mz, b_z,
            W_xr, W_hr, W_mr, b_r,
            W_xh, W_hh, W_mh,
            Wc1T, Wc2T, WdgxT, WdghT, bias1);
    }

    gdecay_kernel<<<dim3(TBr / 32, Ii / 64), 64, 0, stream>>>(Dall, WdgxT, b_dg_x, Gxb, Ii);
    gdecay_kernel<<<dim3(TBr / 32, Hh / 64), 64, 0, stream>>>(Dall, WdghT, b_dg_h, Ghb, Hh);

    xeff_scan_kernel<<<(Bb * Ii) / 256, 256, 0, stream>>>(Xall, Mall, Gxb, xmean, Xe);

    grud_persistent<<<256, 512, 0, stream>>>(
        Xe, Mall, Ghb, Wc1T, Wc2T, bias1, b_h, bn_g, bn_b,
        W_hy, b_hy, rhG, HrawG, PstSum, f1, f2, out_hs, out_ys);
}

// Round 11
// 2294.391 us; speedup vs baseline: 1.2594x; 1.1860x over previous
//
#include <hip/hip_runtime.h>
#include <math.h>

#define Bb 256
#define Ii 128
#define Tt 256
#define Hh 512
#define Oo 2
#define TBr (Tt*Bb)
#define EPS_BN 1e-5f

typedef __attribute__((ext_vector_type(8))) short short8;
typedef __attribute__((ext_vector_type(8))) __bf16 bf16x8;
typedef __attribute__((ext_vector_type(4))) float f32x4;
typedef unsigned long long u64;

__device__ __forceinline__ f32x4 mfma_bf16(short8 a, short8 b, f32x4 c) {
    return __builtin_amdgcn_mfma_f32_16x16x32_bf16(
        __builtin_bit_cast(bf16x8, a), __builtin_bit_cast(bf16x8, b), c, 0, 0, 0);
}
__device__ __forceinline__ short f2bf(float f) {
    union { float f; unsigned u; } v; v.f = f;
    unsigned r = (v.u + 0x7FFFu + ((v.u >> 16) & 1u)) >> 16;
    return (short)r;
}
__device__ __forceinline__ float bf2f(short s) {
    union { unsigned u; float f; } v; v.u = ((unsigned)(unsigned short)s) << 16;
    return v.f;
}
__device__ __forceinline__ float sigmoidf_(float x) { return 1.f / (1.f + expf(-x)); }
__device__ __forceinline__ float softplusf_(float x) { return fmaxf(x, 0.f) + log1pf(expf(-fabsf(x))); }

#define ALD_F(p)  __hip_atomic_load((p),  __ATOMIC_RELAXED, __HIP_MEMORY_SCOPE_AGENT)
#define AST_F(p,v) __hip_atomic_store((p), (v), __ATOMIC_RELAXED, __HIP_MEMORY_SCOPE_AGENT)
#define AADD_F(p,v) (void)__hip_atomic_fetch_add((p), (v), __ATOMIC_RELAXED, __HIP_MEMORY_SCOPE_AGENT)

__device__ __forceinline__ short8 ald16(const short* p) {
    union { u64 u[2]; short8 s; } v;
    v.u[0] = ALD_F((const u64*)p);
    v.u[1] = ALD_F((const u64*)(p + 4));
    return v.s;
}
__device__ __forceinline__ u64 pack4bf(float a, float b, float c_, float d) {
    return (u64)(unsigned short)f2bf(a)
         | ((u64)(unsigned short)f2bf(b) << 16)
         | ((u64)(unsigned short)f2bf(c_) << 32)
         | ((u64)(unsigned short)f2bf(d) << 48);
}

// ---------------------------------------------------------------------------
// repack: input [B,3,I,T] fp32 -> time-major X fp32 [T,B,I], M bf16, D bf16
// ---------------------------------------------------------------------------
__global__ __launch_bounds__(1024) void repack_kernel(const float* __restrict__ in,
                                                      float* __restrict__ Xall,
                                                      short* __restrict__ Mall,
                                                      short* __restrict__ Dall)
{
    __shared__ float tile[32][33];
    const int bz = blockIdx.z;
    const int b = bz / 3, cch = bz % 3;
    const int t0 = blockIdx.x * 32, i0 = blockIdx.y * 32;
    const int tx = threadIdx.x, ty = threadIdx.y;
    const float* src = in + ((size_t)b * 3 + cch) * (size_t)Ii * Tt;
    tile[ty][tx] = src[(size_t)(i0 + ty) * Tt + t0 + tx];
    __syncthreads();
    const float v = tile[tx][ty];
    const size_t off = ((size_t)(t0 + ty) * Bb + b) * Ii + i0 + tx;
    if (cch == 0)      Xall[off] = v;
    else if (cch == 1) Mall[off] = f2bf(v);
    else               Dall[off] = f2bf(v);
}

// ---------------------------------------------------------------------------
// pack weights -> bf16 transposed (n-major, k rows) for MFMA fragments
// ---------------------------------------------------------------------------
__global__ __launch_bounds__(256) void pack_weights_kernel(
    const float* __restrict__ W_dg_x, const float* __restrict__ W_dg_h,
    const float* __restrict__ W_xz, const float* __restrict__ W_hz, const float* __restrict__ W_mz, const float* __restrict__ b_z,
    const float* __restrict__ W_xr, const float* __restrict__ W_hr, const float* __restrict__ W_mr, const float* __restrict__ b_r,
    const float* __restrict__ W_xh, const float* __restrict__ W_hh, const float* __restrict__ W_mh,
    short* __restrict__ Wc1T, short* __restrict__ Wc2T,
    short* __restrict__ WdgxT, short* __restrict__ WdghT, float* __restrict__ bias1)
{
    const int idx = blockIdx.x * blockDim.x + threadIdx.x;
    const int n1 = 1024 * 768, n2 = 512 * 768, n3 = 128 * 128, n4 = 512 * 128;
    if (idx < n1) {
        const int n = idx / 768, k = idx % 768;
        const int col = (n < Hh) ? n : (n - Hh);
        const float* Wx = (n < Hh) ? W_xz : W_xr;
        const float* Wm = (n < Hh) ? W_mz : W_mr;
        const float* Wh = (n < Hh) ? W_hz : W_hr;
        float v;
        if (k < Ii)        v = Wx[(size_t)k * Hh + col];
        else if (k < 2*Ii) v = Wm[(size_t)(k - Ii) * Hh + col];
        else               v = Wh[(size_t)(k - 2*Ii) * Hh + col];
        Wc1T[idx] = f2bf(v);
    } else if (idx < n1 + n2) {
        const int j = idx - n1;
        const int n = j / 768, k = j % 768;
        float v;
        if (k < Ii)        v = W_xh[(size_t)k * Hh + n];
        else if (k < 2*Ii) v = W_mh[(size_t)(k - Ii) * Hh + n];
        else               v = W_hh[(size_t)(k - 2*Ii) * Hh + n];
        Wc2T[j] = f2bf(v);
    } else if (idx < n1 + n2 + n3) {
        const int j = idx - n1 - n2;
        const int n = j >> 7, k = j & 127;
        WdgxT[j] = f2bf(W_dg_x[(size_t)k * Ii + n]);
    } else if (idx < n1 + n2 + n3 + n4) {
        const int j = idx - n1 - n2 - n3;
        const int n = j >> 7, k = j & 127;
        WdghT[j] = f2bf(W_dg_h[(size_t)k * Hh + n]);
    } else if (idx < n1 + n2 + n3 + n4 + 1024) {
        const int n = idx - n1 - n2 - n3 - n4;
        bias1[n] = (n < Hh) ? b_z[n] : b_r[n - Hh];
    }
}

// ---------------------------------------------------------------------------
// gdecay: C = bf16(exp(-relu(A @ B + bias)))
// ---------------------------------------------------------------------------
__global__ __launch_bounds__(64) void gdecay_kernel(const short* __restrict__ A,
                                                    const short* __restrict__ BT,
                                                    const float* __restrict__ bias,
                                                    short* __restrict__ C, int N)
{
    const int lane = threadIdx.x;
    const int c = lane & 15, g = lane >> 4;
    const int m0 = blockIdx.x * 32, n0 = blockIdx.y * 64;
    const short* a0 = A + (size_t)(m0 + c) * Ii + 8 * g;
    const short* a1 = a0 + (size_t)16 * Ii;
    const short* bw = BT + (size_t)(n0 + c) * Ii + 8 * g;
    f32x4 acc[2][4];
    #pragma unroll
    for (int i = 0; i < 2; ++i)
        #pragma unroll
        for (int f = 0; f < 4; ++f) acc[i][f] = (f32x4){0.f, 0.f, 0.f, 0.f};
    #pragma unroll
    for (int k0 = 0; k0 < 128; k0 += 32) {
        const short8 av0 = *(const short8*)(a0 + k0);
        const short8 av1 = *(const short8*)(a1 + k0);
        #pragma unroll
        for (int fn = 0; fn < 4; ++fn) {
            const short8 bv = *(const short8*)(bw + (size_t)fn * 16 * Ii + k0);
            acc[0][fn] = mfma_bf16(av0, bv, acc[0][fn]);
            acc[1][fn] = mfma_bf16(av1, bv, acc[1][fn]);
        }
    }
    #pragma unroll
    for (int fn = 0; fn < 4; ++fn) {
        const int n = n0 + fn * 16 + c;
        const float bs = bias[n];
        #pragma unroll
        for (int fm = 0; fm < 2; ++fm) {
            #pragma unroll
            for (int j = 0; j < 4; ++j) {
                const int m = m0 + fm * 16 + 4 * g + j;
                const float v = expf(-fmaxf(acc[fm][fn][j] + bs, 0.f));
                C[(size_t)m * N + n] = f2bf(v);
            }
        }
    }
}

// ---------------------------------------------------------------------------
// x_last scan + x_eff -> Xe bf16 [T,B,I]
// ---------------------------------------------------------------------------
__global__ __launch_bounds__(256) void xeff_scan_kernel(const float* __restrict__ Xall,
                                                        const short* __restrict__ Mall,
                                                        const short* __restrict__ Gx,
                                                        const float* __restrict__ xmean_p,
                                                        short* __restrict__ Xe)
{
    const int bi = blockIdx.x * blockDim.x + threadIdx.x;
    if (bi >= Bb * Ii) return;
    const float xm = xmean_p[0];
    float xl = 0.f;
    for (int t = 0; t < Tt; ++t) {
        const size_t off = (size_t)t * Bb * Ii + bi;
        const float x = Xall[off];
        const float m = bf2f(Mall[off]);
        const float gx = bf2f(Gx[off]);
        if (m > 0.f) xl = x;
        Xe[off] = f2bf(m * x + (1.f - m) * (gx * xl + (1.f - gx) * xm));
    }
}

// ---------------------------------------------------------------------------
// persistent: 256 blocks x 512 thr. block (mt = bid&15, ng = bid>>4):
// rows m0=mt*16..+16; z cols ng*32; r cols 512+ng*32; htilde cols ng*32.
// Critical-path trims vs r10: concurrent IC issue in stage; out_hs/ys
// deferred to bar1 window (hkeep regs); B epilogue store-before-atomics.
// ---------------------------------------------------------------------------
#define XM_STR 264
#define HP_STR 520
#define GH_STR 520

__global__ __launch_bounds__(512, 1) void grud_persistent(
    const short* __restrict__ Xe, const short* __restrict__ Ma,
    const short* __restrict__ Ghb,
    const short* __restrict__ Wc1T, const short* __restrict__ Wc2T,
    const float* __restrict__ bias1, const float* __restrict__ b_h,
    const float* __restrict__ bn_g, const float* __restrict__ bn_b,
    const float* __restrict__ Why, const float* __restrict__ bhy,
    short* __restrict__ rhG,          // [256][512] bf16  (atomic-only)
    short* __restrict__ HrawG,        // [256][512] bf16  (atomic-only)
    float* __restrict__ PstSum,       // [3][1024] f32    (atomic-only)
    int* __restrict__ f1,             // [256][16] int    (atomic-only)
    int* __restrict__ f2,             // [256][16] int    (atomic-only)
    float* __restrict__ out_hs, float* __restrict__ out_ys)
{
    const int bid = blockIdx.x, tid = threadIdx.x;
    const int w = tid >> 6, lane = tid & 63, c = lane & 15, g = lane >> 4;
    const int mt = bid & 15, ng = bid >> 4;
    const int m0 = mt * 16;

    __shared__ short sXM[16 * XM_STR];       // 8.4 KB
    __shared__ short sHP[16 * HP_STR];       // 16.6 KB
    __shared__ short sGH[16 * GH_STR];       // 16.6 KB
    __shared__ float sZ[32 * 17];            // 2.2 KB  [localcol][row]
    __shared__ float scratch[1536];          // 6 KB k-split reduce
    __shared__ float sWhy[1024];             // 4 KB
    __shared__ float scs[512], shs[512];     // 4 KB
    __shared__ float ysred[16];

    sWhy[tid] = Why[tid]; sWhy[tid + 512] = Why[tid + 512];
    const float bhy0 = bhy[0], bhy1 = bhy[1];

    const int colt = w & 3, kh = w >> 2;             // phase A role
    const int colbaseA = (colt < 2) ? (ng * 32 + colt * 16)
                                    : (512 + ng * 32 + (colt - 2) * 16);
    short8 wA[12];
    {
        const short* bw = Wc1T + (size_t)(colbaseA + c) * 768 + kh * 384 + 8 * g;
        #pragma unroll
        for (int s = 0; s < 12; ++s) wA[s] = *(const short8*)(bw + 32 * s);
    }
    const int colt2 = w & 1, kq = w >> 1;            // phase B role
    const int colbaseB = ng * 32 + colt2 * 16;
    short8 wB[6];
    {
        const short* bw = Wc2T + (size_t)(colbaseB + c) * 768 + kq * 192 + 8 * g;
        #pragma unroll
        for (int s = 0; s < 6; ++s) wB[s] = *(const short8*)(bw + 32 * s);
    }
    // per-wave peer set for fine-grained rh wait
    const int npeer = (kq == 1) ? 4 : (kq >= 2 ? 6 : 0);
    const int peer0 = (kq == 1) ? 0 : (kq == 2 ? 4 : 10);
    const int peerflag = (lane < npeer) ? ((mt + 16 * (peer0 + lane)) * 16) : -1;

    // ---- stage [Xe|Ma] for t=0 ----
    {
        const int r = tid >> 5, cu = tid & 31;
        const short* src = (cu < 16)
            ? (Xe + ((size_t)(m0 + r)) * Ii + 8 * cu)
            : (Ma + ((size_t)(m0 + r)) * Ii + 8 * (cu - 16));
        *(short8*)(&sXM[r * XM_STR + 8 * cu]) = *(const short8*)src;
    }
    __syncthreads();

    float hkeep[16];

    for (int t = 0; t < Tt; ++t) {
        // ======= loop-top: [Xe|Ma]-only MFMA partials ======================
        f32x4 accA = (f32x4){0.f, 0.f, 0.f, 0.f};
        f32x4 accB = (f32x4){0.f, 0.f, 0.f, 0.f};
        if (kh == 0) {
            #pragma unroll
            for (int s = 0; s < 8; ++s)
                accA = mfma_bf16(wA[s],
                    *(const short8*)(&sXM[c * XM_STR + 32 * s + 8 * g]), accA);
        }
        #pragma unroll
        for (int s = 0; s < 6; ++s) {
            const int k = kq * 192 + 32 * s;
            if (k < 256)
                accB = mfma_bf16(wB[s],
                    *(const short8*)(&sXM[c * XM_STR + k + 8 * g]), accB);
        }

        // ======= stage: BN(t-1) scale/shift + hp (outputs deferred) ========
        if (t > 0) {
            const int pR = (t + 2) % 3;               // (t-1) mod 3
            // --- issue ALL independent IC loads up front ---
            u64 hvu[4];
            #pragma unroll
            for (int i = 0; i < 4; ++i) {
                const int idx = tid + i * 512;
                const int r = idx >> 7, c4 = (idx & 127) * 4;
                hvu[i] = ALD_F((const u64*)(HrawG + (size_t)(m0 + r) * Hh + c4));
            }
            const float s1 = ALD_F(&PstSum[pR * 1024 + tid]);
            const float s2 = ALD_F(&PstSum[pR * 1024 + 512 + tid]);
            {
                const float mu = s1 * (1.f / 256.f);
                const float var = fmaxf(s2 * (1.f / 256.f) - mu * mu, 0.f);
                const float sc = bn_g[tid] * rsqrtf(var + EPS_BN);
                scs[tid] = sc; shs[tid] = bn_b[tid] - mu * sc;
            }
            __syncthreads();
            #pragma unroll
            for (int i = 0; i < 4; ++i) {
                const int idx = tid + i * 512;        // u64 granule in 16x128
                const int r = idx >> 7, c4 = (idx & 127) * 4;
                union { u64 u; unsigned short us[4]; } hv, gv;
                hv.u = hvu[i];
                gv.u = *(const u64*)(&sGH[r * GH_STR + c4]);
                float h[4];
                #pragma unroll
                for (int j = 0; j < 4; ++j) {
                    h[j] = fmaf(bf2f((short)hv.us[j]), scs[c4 + j], shs[c4 + j]);
                    hkeep[i * 4 + j] = h[j];
                }
                *(u64*)(&sHP[r * HP_STR + c4]) =
                    pack4bf(h[0] * bf2f((short)gv.us[0]), h[1] * bf2f((short)gv.us[1]),
                            h[2] * bf2f((short)gv.us[2]), h[3] * bf2f((short)gv.us[3]));
            }
            __syncthreads();                          // sHP ready for phase A
        } else {
            #pragma unroll
            for (int i = 0; i < 4; ++i) {
                const int idx = tid + i * 512;
                const int r = idx >> 7, c4 = (idx & 127) * 4;
                *(u64*)(&sHP[r * HP_STR + c4]) = 0ull;
            }
            __syncthreads();
        }

        // ======= Phase A rest: hp part + k-split reduce + epilogue =========
        if (kh == 0) {
            #pragma unroll
            for (int s = 8; s < 12; ++s)
                accA = mfma_bf16(wA[s],
                    *(const short8*)(&sHP[c * HP_STR + (32 * s - 256) + 8 * g]), accA);
        } else {
            #pragma unroll
            for (int s = 0; s < 12; ++s)
                accA = mfma_bf16(wA[s],
                    *(const short8*)(&sHP[c * HP_STR + 128 + 32 * s + 8 * g]), accA);
        }
        if (kh == 1) {
            float* sp = scratch + (colt * 64 + lane) * 4;
            sp[0] = accA[0]; sp[1] = accA[1]; sp[2] = accA[2]; sp[3] = accA[3];
        }
        __syncthreads();
        if (kh == 0) {
            const float* sp = scratch + (colt * 64 + lane) * 4;
            accA[0] += sp[0]; accA[1] += sp[1]; accA[2] += sp[2]; accA[3] += sp[3];
            if (colt < 2) {
                #pragma unroll
                for (int j = 0; j < 4; ++j) {
                    const int lc = colt * 16 + 4 * g + j;
                    const float v = sigmoidf_(accA[j] + bias1[ng * 32 + lc]);
                    sZ[lc * 17 + c] = v;
                }
            } else {
                const int nn0 = ng * 32 + (colt - 2) * 16 + 4 * g;
                float rv[4];
                #pragma unroll
                for (int j = 0; j < 4; ++j) {
                    const float v = sigmoidf_(accA[j] + bias1[512 + nn0 + j]);
                    rv[j] = v * bf2f(sHP[c * HP_STR + nn0 + j]);
                }
                AST_F((u64*)(rhG + ((size_t)(m0 + c) * Hh + nn0)),
                      pack4bf(rv[0], rv[1], rv[2], rv[3]));
            }
        }
        // ---- bar1 arrive ---------------------------------------------------
        __syncthreads();                     // drains rhG stores (vmcnt)
        if (tid == 0) AST_F(&f1[bid * 16], t + 1);
        // ---- bar1 window duties: DEFERRED outputs(t-1), Ghb prefetch, zero -
        if (t > 0) {
            float p0 = 0.f, p1 = 0.f;
            #pragma unroll
            for (int i = 0; i < 4; ++i) {
                const int idx = tid + i * 512;
                const int r = idx >> 7, c4 = (idx & 127) * 4;
                if ((c4 >> 5) == ng) {
                    *(f32x4*)(&out_hs[((size_t)(m0 + r) * Tt + (t - 1)) * Hh + c4]) =
                        (f32x4){hkeep[i*4+0], hkeep[i*4+1], hkeep[i*4+2], hkeep[i*4+3]};
                }
                if (r == ng) {
                    #pragma unroll
                    for (int j = 0; j < 4; ++j) {
                        p0 = fmaf(hkeep[i*4+j], sWhy[2 * (c4 + j)], p0);
                        p1 = fmaf(hkeep[i*4+j], sWhy[2 * (c4 + j) + 1], p1);
                    }
                }
            }
            #pragma unroll
            for (int s = 1; s < 64; s <<= 1) { p0 += __shfl_xor(p0, s); p1 += __shfl_xor(p1, s); }
            if (lane == 0) { ysred[2 * w] = p0; ysred[2 * w + 1] = p1; }
        }
        if (t + 1 < Tt) {
            #pragma unroll
            for (int i = 0; i < 4; ++i) {
                const int idx = tid + i * 512;
                const int r = idx >> 7, c4 = (idx & 127) * 4;
                const u64 v = *(const u64*)(Ghb + ((size_t)(t + 1) * Bb + m0 + r) * Hh + c4);
                *(u64*)(&sGH[r * GH_STR + c4]) = v;
            }
        }
        if (tid < 4) AST_F(&PstSum[((t + 1) % 3) * 1024 + bid * 4 + tid], 0.f);
        if (t > 0) {
            __syncthreads();
            if (tid == 0) {
                float q0 = 0.f, q1 = 0.f;
                #pragma unroll
                for (int i = 0; i < 8; ++i) { q0 += ysred[2 * i]; q1 += ysred[2 * i + 1]; }
                out_ys[((size_t)(m0 + ng) * Tt + (t - 1)) * Oo + 0] = softplusf_(q0 + bhy0);
                out_ys[((size_t)(m0 + ng) * Tt + (t - 1)) * Oo + 1] = softplusf_(q1 + bhy1);
            }
        }

        // ======= Phase B rest: per-wave peer wait + rh MFMAs (direct IC) ===
        if (npeer > 0) {
            for (;;) {
                const int v = (lane < npeer)
                    ? __hip_atomic_load(&f1[peerflag], __ATOMIC_RELAXED, __HIP_MEMORY_SCOPE_AGENT)
                    : 0x7fffffff;
                if (__all(v >= t + 1)) break;
                __builtin_amdgcn_s_sleep(1);
            }
            asm volatile("" ::: "memory");
        }
        #pragma unroll
        for (int s = 0; s < 6; ++s) {
            const int k = kq * 192 + 32 * s;
            if (k >= 256)
                accB = mfma_bf16(wB[s],
                    ald16(rhG + (size_t)(m0 + c) * Hh + (k - 256) + 8 * g), accB);
        }
        if (kq > 0) {
            float* sp = scratch + ((colt2 * 3 + kq - 1) * 64 + lane) * 4;
            sp[0] = accB[0]; sp[1] = accB[1]; sp[2] = accB[2]; sp[3] = accB[3];
        }
        __syncthreads();
        if (kq == 0) {
            #pragma unroll
            for (int qq = 0; qq < 3; ++qq) {
                const float* sp = scratch + ((colt2 * 3 + qq) * 64 + lane) * 4;
                accB[0] += sp[0]; accB[1] += sp[1]; accB[2] += sp[2]; accB[3] += sp[3];
            }
            const int pC = t % 3;
            float hr4[4];
            #pragma unroll
            for (int j = 0; j < 4; ++j) {
                const int lc = colt2 * 16 + 4 * g + j;
                const int col = ng * 32 + lc;
                const float pre = accB[j] + b_h[col];
                const float z = sZ[lc * 17 + c];
                const float hp = bf2f(sHP[c * HP_STR + col]);
                hr4[j] = (1.f - z) * hp + z * tanhf(pre);
            }
            // store first (latency overlaps the reduce+atomics below)
            const int cb = ng * 32 + colt2 * 16 + 4 * g;
            AST_F((u64*)(HrawG + (size_t)(m0 + c) * Hh + cb),
                  pack4bf(hr4[0], hr4[1], hr4[2], hr4[3]));
            #pragma unroll
            for (int j = 0; j < 4; ++j) {
                float sp_ = hr4[j], sq_ = hr4[j] * hr4[j];
                sp_ += __shfl_xor(sp_, 1); sq_ += __shfl_xor(sq_, 1);
                sp_ += __shfl_xor(sp_, 2); sq_ += __shfl_xor(sq_, 2);
                sp_ += __shfl_xor(sp_, 4); sq_ += __shfl_xor(sq_, 4);
                sp_ += __shfl_xor(sp_, 8); sq_ += __shfl_xor(sq_, 8);
                if (c == 0) {
                    const int col = ng * 32 + colt2 * 16 + 4 * g + j;
                    AADD_F(&PstSum[pC * 1024 + col], sp_);
                    AADD_F(&PstSum[pC * 1024 + 512 + col], sq_);
                }
            }
        }
        // ---- bar2: global barrier (gates stats + HrawG), 1-wave poll ------
        __syncthreads();
        if (tid == 0) AST_F(&f2[bid * 16], t + 1);
        if (t + 1 < Tt) {
            const int r = tid >> 5, cu = tid & 31;
            const short* src = (cu < 16)
                ? (Xe + ((size_t)(t + 1) * Bb + m0 + r) * Ii + 8 * cu)
                : (Ma + ((size_t)(t + 1) * Bb + m0 + r) * Ii + 8 * (cu - 16));
            *(short8*)(&sXM[r * XM_STR + 8 * cu]) = *(const short8*)src;
        }
        if (tid < 64) {
            for (;;) {
                const int v0 = __hip_atomic_load(&f2[(tid * 4 + 0) * 16], __ATOMIC_RELAXED, __HIP_MEMORY_SCOPE_AGENT);
                const int v1 = __hip_atomic_load(&f2[(tid * 4 + 1) * 16], __ATOMIC_RELAXED, __HIP_MEMORY_SCOPE_AGENT);
                const int v2 = __hip_atomic_load(&f2[(tid * 4 + 2) * 16], __ATOMIC_RELAXED, __HIP_MEMORY_SCOPE_AGENT);
                const int v3 = __hip_atomic_load(&f2[(tid * 4 + 3) * 16], __ATOMIC_RELAXED, __HIP_MEMORY_SCOPE_AGENT);
                int mn = v0 < v1 ? v0 : v1;
                mn = mn < v2 ? mn : v2;
                mn = mn < v3 ? mn : v3;
                if (__all(mn >= t + 1)) break;
                __builtin_amdgcn_s_sleep(1);
            }
        }
        __syncthreads();
    }

    // ================= tail: BN + outputs for t = Tt-1 =====================
    {
        const int pR = (Tt - 1) % 3;
        {
            const float s1 = ALD_F(&PstSum[pR * 1024 + tid]);
            const float s2 = ALD_F(&PstSum[pR * 1024 + 512 + tid]);
            const float mu = s1 * (1.f / 256.f);
            const float var = fmaxf(s2 * (1.f / 256.f) - mu * mu, 0.f);
            const float sc = bn_g[tid] * rsqrtf(var + EPS_BN);
            scs[tid] = sc; shs[tid] = bn_b[tid] - mu * sc;
        }
        __syncthreads();
        float p0 = 0.f, p1 = 0.f;
        #pragma unroll
        for (int i = 0; i < 4; ++i) {
            const int idx = tid + i * 512;
            const int r = idx >> 7, c4 = (idx & 127) * 4;
            union { u64 u; unsigned short us[4]; } hv;
            hv.u = ALD_F((const u64*)(HrawG + (size_t)(m0 + r) * Hh + c4));
            float h[4];
            #pragma unroll
            for (int j = 0; j < 4; ++j)
                h[j] = fmaf(bf2f((short)hv.us[j]), scs[c4 + j], shs[c4 + j]);
            if ((c4 >> 5) == ng) {
                *(f32x4*)(&out_hs[((size_t)(m0 + r) * Tt + (Tt - 1)) * Hh + c4]) =
                    (f32x4){h[0], h[1], h[2], h[3]};
            }
            if (r == ng) {
                #pragma unroll
                for (int j = 0; j < 4; ++j) {
                    p0 = fmaf(h[j], sWhy[2 * (c4 + j)], p0);
                    p1 = fmaf(h[j], sWhy[2 * (c4 + j) + 1], p1);
                }
            }
        }
        #pragma unroll
        for (int s = 1; s < 64; s <<= 1) { p0 += __shfl_xor(p0, s); p1 += __shfl_xor(p1, s); }
        if (lane == 0) { ysred[2 * w] = p0; ysred[2 * w + 1] = p1; }
        __syncthreads();
        if (tid == 0) {
            float q0 = 0.f, q1 = 0.f;
            #pragma unroll
            for (int i = 0; i < 8; ++i) { q0 += ysred[2 * i]; q1 += ysred[2 * i + 1]; }
            out_ys[((size_t)(m0 + ng) * Tt + (Tt - 1)) * Oo + 0] = softplusf_(q0 + bhy0);
            out_ys[((size_t)(m0 + ng) * Tt + (Tt - 1)) * Oo + 1] = softplusf_(q1 + bhy1);
        }
    }
}

// ---------------------------------------------------------------------------
extern "C" void kernel_launch(void* const* d_in, const int* in_sizes, int n_in,
                              void* d_out, int out_size, void* d_ws, size_t ws_size,
                              hipStream_t stream)
{
    const float* input  = (const float*)d_in[0];
    const float* xmean  = (const float*)d_in[1];
    const float* W_dg_x = (const float*)d_in[2];
    const float* b_dg_x = (const float*)d_in[3];
    const float* W_dg_h = (const float*)d_in[4];
    const float* b_dg_h = (const float*)d_in[5];
    const float* W_xz   = (const float*)d_in[6];
    const float* W_hz   = (const float*)d_in[7];
    const float* W_mz   = (const float*)d_in[8];
    const float* b_z    = (const float*)d_in[9];
    const float* W_xr   = (const float*)d_in[10];
    const float* W_hr   = (const float*)d_in[11];
    const float* W_mr   = (const float*)d_in[12];
    const float* b_r    = (const float*)d_in[13];
    const float* W_xh   = (const float*)d_in[14];
    const float* W_hh   = (const float*)d_in[15];
    const float* W_mh   = (const float*)d_in[16];
    const float* b_h    = (const float*)d_in[17];
    const float* W_hy   = (const float*)d_in[18];
    const float* b_hy   = (const float*)d_in[19];
    const float* bn_g   = (const float*)d_in[20];
    const float* bn_b   = (const float*)d_in[21];

    float* out_ys = (float*)d_out;
    float* out_hs = out_ys + (size_t)Bb * Tt * Oo;

    char* p = (char*)d_ws;
    float* Xall = (float*)p;            p += (size_t)TBr * Ii * 4;
    short* Mall = (short*)p;            p += (size_t)TBr * Ii * 2;
    short* Dall = (short*)p;            p += (size_t)TBr * Ii * 2;
    short* Gxb  = (short*)p;            p += (size_t)TBr * Ii * 2;
    short* Ghb  = (short*)p;            p += (size_t)TBr * Hh * 2;
    short* Xe   = (short*)p;            p += (size_t)TBr * Ii * 2;
    short* Wc1T = (short*)p;            p += (size_t)1024 * 768 * 2;
    short* Wc2T = (short*)p;            p += (size_t)512 * 768 * 2;
    short* WdgxT= (short*)p;            p += (size_t)128 * 128 * 2;
    short* WdghT= (short*)p;            p += (size_t)512 * 128 * 2;
    float* bias1= (float*)p;            p += 1024 * 4;
    short* rhG  = (short*)p;            p += (size_t)Bb * Hh * 2;
    short* HrawG= (short*)p;            p += (size_t)Bb * Hh * 2;
    float* PstSum=(float*)p;            p += 3 * 1024 * 4;
    int*   f1   = (int*)p;              p += 256 * 16 * 4;
    int*   f2   = (int*)p;              p += 256 * 16 * 4;

    hipMemsetAsync(f1, 0, 256 * 16 * 4, stream);
    hipMemsetAsync(f2, 0, 256 * 16 * 4, stream);
    hipMemsetAsync(PstSum, 0, 3 * 1024 * 4, stream);

    repack_kernel<<<dim3(Tt / 32, Ii / 32, Bb * 3), dim3(32, 32), 0, stream>>>(input, Xall, Mall, Dall);

    {
        const int total = 1024 * 768 + 512 * 768 + 128 * 128 + 512 * 128 + 1024;
        pack_weights_kernel<<<(total + 255) / 256, 256, 0, stream>>>(
            W_dg_x, W_dg_h,
            W_xz, W_hz, W_mz, b_z,
            W_xr, W_hr, W_mr, b_r,
            W_xh, W_hh, W_mh,
            Wc1T, Wc2T, WdgxT, WdghT, bias1);
    }

    gdecay_kernel<<<dim3(TBr / 32, Ii / 64), 64, 0, stream>>>(Dall, WdgxT, b_dg_x, Gxb, Ii);
    gdecay_kernel<<<dim3(TBr / 32, Hh / 64), 64, 0, stream>>>(Dall, WdghT, b_dg_h, Ghb, Hh);

    xeff_scan_kernel<<<(Bb * Ii) / 256, 256, 0, stream>>>(Xall, Mall, Gxb, xmean, Xe);

    grud_persistent<<<256, 512, 0, stream>>>(
        Xe, Mall, Ghb, Wc1T, Wc2T, bias1, b_h, bn_g, bn_b,
        W_hy, b_hy, rhG, HrawG, PstSum, f1, f2, out_hs, out_ys);
}

// Round 12
// 2245.946 us; speedup vs baseline: 1.2866x; 1.0216x over previous
//
#include <hip/hip_runtime.h>
#include <math.h>

#define Bb 256
#define Ii 128
#define Tt 256
#define Hh 512
#define Oo 2
#define TBr (Tt*Bb)
#define EPS_BN 1e-5f

typedef __attribute__((ext_vector_type(8))) short short8;
typedef __attribute__((ext_vector_type(8))) __bf16 bf16x8;
typedef __attribute__((ext_vector_type(4))) float f32x4;
typedef unsigned long long u64;

__device__ __forceinline__ f32x4 mfma_bf16(short8 a, short8 b, f32x4 c) {
    return __builtin_amdgcn_mfma_f32_16x16x32_bf16(
        __builtin_bit_cast(bf16x8, a), __builtin_bit_cast(bf16x8, b), c, 0, 0, 0);
}
__device__ __forceinline__ short f2bf(float f) {
    union { float f; unsigned u; } v; v.f = f;
    unsigned r = (v.u + 0x7FFFu + ((v.u >> 16) & 1u)) >> 16;
    return (short)r;
}
__device__ __forceinline__ float bf2f(short s) {
    union { unsigned u; float f; } v; v.u = ((unsigned)(unsigned short)s) << 16;
    return v.f;
}
__device__ __forceinline__ float sigmoidf_(float x) { return 1.f / (1.f + expf(-x)); }
__device__ __forceinline__ float softplusf_(float x) { return fmaxf(x, 0.f) + log1pf(expf(-fabsf(x))); }

#define ALD_F(p)  __hip_atomic_load((p),  __ATOMIC_RELAXED, __HIP_MEMORY_SCOPE_AGENT)
#define AST_F(p,v) __hip_atomic_store((p), (v), __ATOMIC_RELAXED, __HIP_MEMORY_SCOPE_AGENT)
#define AADD_F(p,v) (void)__hip_atomic_fetch_add((p), (v), __ATOMIC_RELAXED, __HIP_MEMORY_SCOPE_AGENT)

__device__ __forceinline__ short8 ald16(const short* p) {
    union { u64 u[2]; short8 s; } v;
    v.u[0] = ALD_F((const u64*)p);
    v.u[1] = ALD_F((const u64*)(p + 4));
    return v.s;
}
__device__ __forceinline__ u64 pack4bf(float a, float b, float c_, float d) {
    return (u64)(unsigned short)f2bf(a)
         | ((u64)(unsigned short)f2bf(b) << 16)
         | ((u64)(unsigned short)f2bf(c_) << 32)
         | ((u64)(unsigned short)f2bf(d) << 48);
}

// ---------------------------------------------------------------------------
// repack: input [B,3,I,T] fp32 -> time-major X fp32 [T,B,I], M bf16, D bf16
// ---------------------------------------------------------------------------
__global__ __launch_bounds__(1024) void repack_kernel(const float* __restrict__ in,
                                                      float* __restrict__ Xall,
                                                      short* __restrict__ Mall,
                                                      short* __restrict__ Dall)
{
    __shared__ float tile[32][33];
    const int bz = blockIdx.z;
    const int b = bz / 3, cch = bz % 3;
    const int t0 = blockIdx.x * 32, i0 = blockIdx.y * 32;
    const int tx = threadIdx.x, ty = threadIdx.y;
    const float* src = in + ((size_t)b * 3 + cch) * (size_t)Ii * Tt;
    tile[ty][tx] = src[(size_t)(i0 + ty) * Tt + t0 + tx];
    __syncthreads();
    const float v = tile[tx][ty];
    const size_t off = ((size_t)(t0 + ty) * Bb + b) * Ii + i0 + tx;
    if (cch == 0)      Xall[off] = v;
    else if (cch == 1) Mall[off] = f2bf(v);
    else               Dall[off] = f2bf(v);
}

// ---------------------------------------------------------------------------
// pack weights -> bf16 transposed (n-major, k rows) for MFMA fragments
// ---------------------------------------------------------------------------
__global__ __launch_bounds__(256) void pack_weights_kernel(
    const float* __restrict__ W_dg_x, const float* __restrict__ W_dg_h,
    const float* __restrict__ W_xz, const float* __restrict__ W_hz, const float* __restrict__ W_mz, const float* __restrict__ b_z,
    const float* __restrict__ W_xr, const float* __restrict__ W_hr, const float* __restrict__ W_mr, const float* __restrict__ b_r,
    const float* __restrict__ W_xh, const float* __restrict__ W_hh, const float* __restrict__ W_mh,
    short* __restrict__ Wc1T, short* __restrict__ Wc2T,
    short* __restrict__ WdgxT, short* __restrict__ WdghT, float* __restrict__ bias1)
{
    const int idx = blockIdx.x * blockDim.x + threadIdx.x;
    const int n1 = 1024 * 768, n2 = 512 * 768, n3 = 128 * 128, n4 = 512 * 128;
    if (idx < n1) {
        const int n = idx / 768, k = idx % 768;
        const int col = (n < Hh) ? n : (n - Hh);
        const float* Wx = (n < Hh) ? W_xz : W_xr;
        const float* Wm = (n < Hh) ? W_mz : W_mr;
        const float* Wh = (n < Hh) ? W_hz : W_hr;
        float v;
        if (k < Ii)        v = Wx[(size_t)k * Hh + col];
        else if (k < 2*Ii) v = Wm[(size_t)(k - Ii) * Hh + col];
        else               v = Wh[(size_t)(k - 2*Ii) * Hh + col];
        Wc1T[idx] = f2bf(v);
    } else if (idx < n1 + n2) {
        const int j = idx - n1;
        const int n = j / 768, k = j % 768;
        float v;
        if (k < Ii)        v = W_xh[(size_t)k * Hh + n];
        else if (k < 2*Ii) v = W_mh[(size_t)(k - Ii) * Hh + n];
        else               v = W_hh[(size_t)(k - 2*Ii) * Hh + n];
        Wc2T[j] = f2bf(v);
    } else if (idx < n1 + n2 + n3) {
        const int j = idx - n1 - n2;
        const int n = j >> 7, k = j & 127;
        WdgxT[j] = f2bf(W_dg_x[(size_t)k * Ii + n]);
    } else if (idx < n1 + n2 + n3 + n4) {
        const int j = idx - n1 - n2 - n3;
        const int n = j >> 7, k = j & 127;
        WdghT[j] = f2bf(W_dg_h[(size_t)k * Hh + n]);
    } else if (idx < n1 + n2 + n3 + n4 + 1024) {
        const int n = idx - n1 - n2 - n3 - n4;
        bias1[n] = (n < Hh) ? b_z[n] : b_r[n - Hh];
    }
}

// ---------------------------------------------------------------------------
// gdecay: C = bf16(exp(-relu(A @ B + bias)))
// ---------------------------------------------------------------------------
__global__ __launch_bounds__(64) void gdecay_kernel(const short* __restrict__ A,
                                                    const short* __restrict__ BT,
                                                    const float* __restrict__ bias,
                                                    short* __restrict__ C, int N)
{
    const int lane = threadIdx.x;
    const int c = lane & 15, g = lane >> 4;
    const int m0 = blockIdx.x * 32, n0 = blockIdx.y * 64;
    const short* a0 = A + (size_t)(m0 + c) * Ii + 8 * g;
    const short* a1 = a0 + (size_t)16 * Ii;
    const short* bw = BT + (size_t)(n0 + c) * Ii + 8 * g;
    f32x4 acc[2][4];
    #pragma unroll
    for (int i = 0; i < 2; ++i)
        #pragma unroll
        for (int f = 0; f < 4; ++f) acc[i][f] = (f32x4){0.f, 0.f, 0.f, 0.f};
    #pragma unroll
    for (int k0 = 0; k0 < 128; k0 += 32) {
        const short8 av0 = *(const short8*)(a0 + k0);
        const short8 av1 = *(const short8*)(a1 + k0);
        #pragma unroll
        for (int fn = 0; fn < 4; ++fn) {
            const short8 bv = *(const short8*)(bw + (size_t)fn * 16 * Ii + k0);
            acc[0][fn] = mfma_bf16(av0, bv, acc[0][fn]);
            acc[1][fn] = mfma_bf16(av1, bv, acc[1][fn]);
        }
    }
    #pragma unroll
    for (int fn = 0; fn < 4; ++fn) {
        const int n = n0 + fn * 16 + c;
        const float bs = bias[n];
        #pragma unroll
        for (int fm = 0; fm < 2; ++fm) {
            #pragma unroll
            for (int j = 0; j < 4; ++j) {
                const int m = m0 + fm * 16 + 4 * g + j;
                const float v = expf(-fmaxf(acc[fm][fn][j] + bs, 0.f));
                C[(size_t)m * N + n] = f2bf(v);
            }
        }
    }
}

// ---------------------------------------------------------------------------
// x_last scan + x_eff -> Xe bf16 [T,B,I]
// ---------------------------------------------------------------------------
__global__ __launch_bounds__(256) void xeff_scan_kernel(const float* __restrict__ Xall,
                                                        const short* __restrict__ Mall,
                                                        const short* __restrict__ Gx,
                                                        const float* __restrict__ xmean_p,
                                                        short* __restrict__ Xe)
{
    const int bi = blockIdx.x * blockDim.x + threadIdx.x;
    if (bi >= Bb * Ii) return;
    const float xm = xmean_p[0];
    float xl = 0.f;
    for (int t = 0; t < Tt; ++t) {
        const size_t off = (size_t)t * Bb * Ii + bi;
        const float x = Xall[off];
        const float m = bf2f(Mall[off]);
        const float gx = bf2f(Gx[off]);
        if (m > 0.f) xl = x;
        Xe[off] = f2bf(m * x + (1.f - m) * (gx * xl + (1.f - gx) * xm));
    }
}

// ---------------------------------------------------------------------------
// persistent: 256 blocks x 512 thr. block (mt = bid&15, ng = bid>>4):
// rows m0=mt*16..+16; z cols ng*32; r cols 512+ng*32; htilde cols ng*32.
// r12: private BN (no scs LDS, 1 stage sync), ysred sync removed (tid256
// combine after post-B sync), gamma/beta in LDS, IC loads at loop top.
// ---------------------------------------------------------------------------
#define XM_STR 264
#define HP_STR 520
#define GH_STR 520

__global__ __launch_bounds__(512, 1) void grud_persistent(
    const short* __restrict__ Xe, const short* __restrict__ Ma,
    const short* __restrict__ Ghb,
    const short* __restrict__ Wc1T, const short* __restrict__ Wc2T,
    const float* __restrict__ bias1, const float* __restrict__ b_h,
    const float* __restrict__ bn_g, const float* __restrict__ bn_b,
    const float* __restrict__ Why, const float* __restrict__ bhy,
    short* __restrict__ rhG,          // [256][512] bf16  (atomic-only)
    short* __restrict__ HrawG,        // [256][512] bf16  (atomic-only)
    float* __restrict__ PstSum,       // [3][1024] f32    (atomic-only)
    int* __restrict__ f1,             // [256][16] int    (atomic-only)
    int* __restrict__ f2,             // [256][16] int    (atomic-only)
    float* __restrict__ out_hs, float* __restrict__ out_ys)
{
    const int bid = blockIdx.x, tid = threadIdx.x;
    const int w = tid >> 6, lane = tid & 63, c = lane & 15, g = lane >> 4;
    const int mt = bid & 15, ng = bid >> 4;
    const int m0 = mt * 16;

    __shared__ short sXM[16 * XM_STR];       // 8.4 KB
    __shared__ short sHP[16 * HP_STR];       // 16.6 KB
    __shared__ short sGH[16 * GH_STR];       // 16.6 KB
    __shared__ float sZ[32 * 17];            // 2.2 KB  [localcol][row]
    __shared__ float scratch[1536];          // 6 KB k-split reduce
    __shared__ float sWhy[1024];             // 4 KB
    __shared__ float sBg[512], sBb[512];     // 4 KB gamma/beta
    __shared__ float ysred[16];

    sWhy[tid] = Why[tid]; sWhy[tid + 512] = Why[tid + 512];
    sBg[tid] = bn_g[tid]; sBb[tid] = bn_b[tid];
    const float bhy0 = bhy[0], bhy1 = bhy[1];

    const int colt = w & 3, kh = w >> 2;             // phase A role
    const int colbaseA = (colt < 2) ? (ng * 32 + colt * 16)
                                    : (512 + ng * 32 + (colt - 2) * 16);
    short8 wA[12];
    {
        const short* bw = Wc1T + (size_t)(colbaseA + c) * 768 + kh * 384 + 8 * g;
        #pragma unroll
        for (int s = 0; s < 12; ++s) wA[s] = *(const short8*)(bw + 32 * s);
    }
    const int colt2 = w & 1, kq = w >> 1;            // phase B role
    const int colbaseB = ng * 32 + colt2 * 16;
    short8 wB[6];
    {
        const short* bw = Wc2T + (size_t)(colbaseB + c) * 768 + kq * 192 + 8 * g;
        #pragma unroll
        for (int s = 0; s < 6; ++s) wB[s] = *(const short8*)(bw + 32 * s);
    }
    // per-wave peer set for fine-grained rh wait
    const int npeer = (kq == 1) ? 4 : (kq >= 2 ? 6 : 0);
    const int peer0 = (kq == 1) ? 0 : (kq == 2 ? 4 : 10);
    const int peerflag = (lane < npeer) ? ((mt + 16 * (peer0 + lane)) * 16) : -1;

    // per-thread fixed 4-column group: (tid + i*512) & 127 is i-invariant
    const int c4s = (tid & 127) * 4;
    const int rb0 = tid >> 7;                        // base row; rows rb0+4i
    const bool myng = (c4s >> 5) == ng;

    // ---- stage [Xe|Ma] for t=0 ----
    {
        const int r = tid >> 5, cu = tid & 31;
        const short* src = (cu < 16)
            ? (Xe + ((size_t)(m0 + r)) * Ii + 8 * cu)
            : (Ma + ((size_t)(m0 + r)) * Ii + 8 * (cu - 16));
        *(short8*)(&sXM[r * XM_STR + 8 * cu]) = *(const short8*)src;
    }
    __syncthreads();

    float hkeep[16];

    for (int t = 0; t < Tt; ++t) {
        // ======= issue ALL stage IC loads first (latency under MFMAs) ======
        u64 hvu[4];
        u64 s1a = 0, s1b = 0, s2a = 0, s2b = 0;
        if (t > 0) {
            const int pR = (t + 2) % 3;
            #pragma unroll
            for (int i = 0; i < 4; ++i)
                hvu[i] = ALD_F((const u64*)(HrawG + (size_t)(m0 + rb0 + 4 * i) * Hh + c4s));
            s1a = ALD_F((const u64*)&PstSum[pR * 1024 + c4s]);
            s1b = ALD_F((const u64*)&PstSum[pR * 1024 + c4s + 2]);
            s2a = ALD_F((const u64*)&PstSum[pR * 1024 + 512 + c4s]);
            s2b = ALD_F((const u64*)&PstSum[pR * 1024 + 512 + c4s + 2]);
        }

        // ======= loop-top: [Xe|Ma]-only MFMA partials ======================
        f32x4 accA = (f32x4){0.f, 0.f, 0.f, 0.f};
        f32x4 accB = (f32x4){0.f, 0.f, 0.f, 0.f};
        if (kh == 0) {
            #pragma unroll
            for (int s = 0; s < 8; ++s)
                accA = mfma_bf16(wA[s],
                    *(const short8*)(&sXM[c * XM_STR + 32 * s + 8 * g]), accA);
        }
        #pragma unroll
        for (int s = 0; s < 6; ++s) {
            const int k = kq * 192 + 32 * s;
            if (k < 256)
                accB = mfma_bf16(wB[s],
                    *(const short8*)(&sXM[c * XM_STR + k + 8 * g]), accB);
        }

        // ======= stage consume: private BN + hp (outputs deferred) =========
        if (t > 0) {
            union { u64 u; float f[2]; } ua, ub;
            float sc4[4], sh4[4];
            {
                float sum4[4], sq4[4];
                ua.u = s1a; ub.u = s1b;
                sum4[0] = ua.f[0]; sum4[1] = ua.f[1]; sum4[2] = ub.f[0]; sum4[3] = ub.f[1];
                ua.u = s2a; ub.u = s2b;
                sq4[0] = ua.f[0]; sq4[1] = ua.f[1]; sq4[2] = ub.f[0]; sq4[3] = ub.f[1];
                #pragma unroll
                for (int j = 0; j < 4; ++j) {
                    const float mu = sum4[j] * (1.f / 256.f);
                    const float var = fmaxf(sq4[j] * (1.f / 256.f) - mu * mu, 0.f);
                    const float sc = sBg[c4s + j] * rsqrtf(var + EPS_BN);
                    sc4[j] = sc; sh4[j] = sBb[c4s + j] - mu * sc;
                }
            }
            #pragma unroll
            for (int i = 0; i < 4; ++i) {
                const int r = rb0 + 4 * i;
                union { u64 u; unsigned short us[4]; } hv, gv;
                hv.u = hvu[i];
                gv.u = *(const u64*)(&sGH[r * GH_STR + c4s]);
                float h[4];
                #pragma unroll
                for (int j = 0; j < 4; ++j) {
                    h[j] = fmaf(bf2f((short)hv.us[j]), sc4[j], sh4[j]);
                    hkeep[i * 4 + j] = h[j];
                }
                *(u64*)(&sHP[r * HP_STR + c4s]) =
                    pack4bf(h[0] * bf2f((short)gv.us[0]), h[1] * bf2f((short)gv.us[1]),
                            h[2] * bf2f((short)gv.us[2]), h[3] * bf2f((short)gv.us[3]));
            }
        } else {
            #pragma unroll
            for (int i = 0; i < 4; ++i)
                *(u64*)(&sHP[(rb0 + 4 * i) * HP_STR + c4s]) = 0ull;
        }
        __syncthreads();                              // sHP ready for phase A

        // ======= Phase A rest: hp part + k-split reduce + epilogue =========
        if (kh == 0) {
            #pragma unroll
            for (int s = 8; s < 12; ++s)
                accA = mfma_bf16(wA[s],
                    *(const short8*)(&sHP[c * HP_STR + (32 * s - 256) + 8 * g]), accA);
        } else {
            #pragma unroll
            for (int s = 0; s < 12; ++s)
                accA = mfma_bf16(wA[s],
                    *(const short8*)(&sHP[c * HP_STR + 128 + 32 * s + 8 * g]), accA);
        }
        if (kh == 1) {
            float* sp = scratch + (colt * 64 + lane) * 4;
            sp[0] = accA[0]; sp[1] = accA[1]; sp[2] = accA[2]; sp[3] = accA[3];
        }
        __syncthreads();
        if (kh == 0) {
            const float* sp = scratch + (colt * 64 + lane) * 4;
            accA[0] += sp[0]; accA[1] += sp[1]; accA[2] += sp[2]; accA[3] += sp[3];
            if (colt < 2) {
                #pragma unroll
                for (int j = 0; j < 4; ++j) {
                    const int lc = colt * 16 + 4 * g + j;
                    const float v = sigmoidf_(accA[j] + bias1[ng * 32 + lc]);
                    sZ[lc * 17 + c] = v;
                }
            } else {
                const int nn0 = ng * 32 + (colt - 2) * 16 + 4 * g;
                float rv[4];
                #pragma unroll
                for (int j = 0; j < 4; ++j) {
                    const float v = sigmoidf_(accA[j] + bias1[512 + nn0 + j]);
                    rv[j] = v * bf2f(sHP[c * HP_STR + nn0 + j]);
                }
                AST_F((u64*)(rhG + ((size_t)(m0 + c) * Hh + nn0)),
                      pack4bf(rv[0], rv[1], rv[2], rv[3]));
            }
        }
        // ---- bar1 arrive ---------------------------------------------------
        __syncthreads();                     // drains rhG stores (vmcnt)
        if (tid == 0) AST_F(&f1[bid * 16], t + 1);
        // ---- bar1 window duties: DEFERRED outputs(t-1), Ghb prefetch, zero -
        if (t > 0) {
            float p0 = 0.f, p1 = 0.f;
            #pragma unroll
            for (int i = 0; i < 4; ++i) {
                const int r = rb0 + 4 * i;
                if (myng) {
                    *(f32x4*)(&out_hs[((size_t)(m0 + r) * Tt + (t - 1)) * Hh + c4s]) =
                        (f32x4){hkeep[i*4+0], hkeep[i*4+1], hkeep[i*4+2], hkeep[i*4+3]};
                }
                if (r == ng) {
                    #pragma unroll
                    for (int j = 0; j < 4; ++j) {
                        p0 = fmaf(hkeep[i*4+j], sWhy[2 * (c4s + j)], p0);
                        p1 = fmaf(hkeep[i*4+j], sWhy[2 * (c4s + j) + 1], p1);
                    }
                }
            }
            #pragma unroll
            for (int s = 1; s < 64; s <<= 1) { p0 += __shfl_xor(p0, s); p1 += __shfl_xor(p1, s); }
            if (lane == 0) { ysred[2 * w] = p0; ysred[2 * w + 1] = p1; }
        }
        if (t + 1 < Tt) {
            #pragma unroll
            for (int i = 0; i < 4; ++i) {
                const int r = rb0 + 4 * i;
                const u64 v = *(const u64*)(Ghb + ((size_t)(t + 1) * Bb + m0 + r) * Hh + c4s);
                *(u64*)(&sGH[r * GH_STR + c4s]) = v;
            }
        }
        if (tid < 4) AST_F(&PstSum[((t + 1) % 3) * 1024 + bid * 4 + tid], 0.f);

        // ======= Phase B rest: per-wave peer wait + rh MFMAs (direct IC) ===
        if (npeer > 0) {
            for (;;) {
                const int v = (lane < npeer)
                    ? __hip_atomic_load(&f1[peerflag], __ATOMIC_RELAXED, __HIP_MEMORY_SCOPE_AGENT)
                    : 0x7fffffff;
                if (__all(v >= t + 1)) break;
                __builtin_amdgcn_s_sleep(1);
            }
            asm volatile("" ::: "memory");
        }
        #pragma unroll
        for (int s = 0; s < 6; ++s) {
            const int k = kq * 192 + 32 * s;
            if (k >= 256)
                accB = mfma_bf16(wB[s],
                    ald16(rhG + (size_t)(m0 + c) * Hh + (k - 256) + 8 * g), accB);
        }
        if (kq > 0) {
            float* sp = scratch + ((colt2 * 3 + kq - 1) * 64 + lane) * 4;
            sp[0] = accB[0]; sp[1] = accB[1]; sp[2] = accB[2]; sp[3] = accB[3];
        }
        __syncthreads();
        // ---- deferred ys(t-1) combine by an idle (non-epilogue) thread ----
        if (t > 0 && tid == 256) {
            float q0 = 0.f, q1 = 0.f;
            #pragma unroll
            for (int i = 0; i < 8; ++i) { q0 += ysred[2 * i]; q1 += ysred[2 * i + 1]; }
            out_ys[((size_t)(m0 + ng) * Tt + (t - 1)) * Oo + 0] = softplusf_(q0 + bhy0);
            out_ys[((size_t)(m0 + ng) * Tt + (t - 1)) * Oo + 1] = softplusf_(q1 + bhy1);
        }
        if (kq == 0) {
            #pragma unroll
            for (int qq = 0; qq < 3; ++qq) {
                const float* sp = scratch + ((colt2 * 3 + qq) * 64 + lane) * 4;
                accB[0] += sp[0]; accB[1] += sp[1]; accB[2] += sp[2]; accB[3] += sp[3];
            }
            const int pC = t % 3;
            float hr4[4];
            #pragma unroll
            for (int j = 0; j < 4; ++j) {
                const int lc = colt2 * 16 + 4 * g + j;
                const int col = ng * 32 + lc;
                const float pre = accB[j] + b_h[col];
                const float z = sZ[lc * 17 + c];
                const float hp = bf2f(sHP[c * HP_STR + col]);
                hr4[j] = (1.f - z) * hp + z * tanhf(pre);
            }
            // store first (latency overlaps the reduce+atomics below)
            const int cb = ng * 32 + colt2 * 16 + 4 * g;
            AST_F((u64*)(HrawG + (size_t)(m0 + c) * Hh + cb),
                  pack4bf(hr4[0], hr4[1], hr4[2], hr4[3]));
            #pragma unroll
            for (int j = 0; j < 4; ++j) {
                float sp_ = hr4[j], sq_ = hr4[j] * hr4[j];
                sp_ += __shfl_xor(sp_, 1); sq_ += __shfl_xor(sq_, 1);
                sp_ += __shfl_xor(sp_, 2); sq_ += __shfl_xor(sq_, 2);
                sp_ += __shfl_xor(sp_, 4); sq_ += __shfl_xor(sq_, 4);
                sp_ += __shfl_xor(sp_, 8); sq_ += __shfl_xor(sq_, 8);
                if (c == 0) {
                    const int col = ng * 32 + colt2 * 16 + 4 * g + j;
                    AADD_F(&PstSum[pC * 1024 + col], sp_);
                    AADD_F(&PstSum[pC * 1024 + 512 + col], sq_);
                }
            }
        }
        // ---- bar2: global barrier (gates stats + HrawG), 1-wave poll ------
        __syncthreads();
        if (tid == 0) AST_F(&f2[bid * 16], t + 1);
        if (t + 1 < Tt) {
            const int r = tid >> 5, cu = tid & 31;
            const short* src = (cu < 16)
                ? (Xe + ((size_t)(t + 1) * Bb + m0 + r) * Ii + 8 * cu)
                : (Ma + ((size_t)(t + 1) * Bb + m0 + r) * Ii + 8 * (cu - 16));
            *(short8*)(&sXM[r * XM_STR + 8 * cu]) = *(const short8*)src;
        }
        if (tid < 64) {
            for (;;) {
                const int v0 = __hip_atomic_load(&f2[(tid * 4 + 0) * 16], __ATOMIC_RELAXED, __HIP_MEMORY_SCOPE_AGENT);
                const int v1 = __hip_atomic_load(&f2[(tid * 4 + 1) * 16], __ATOMIC_RELAXED, __HIP_MEMORY_SCOPE_AGENT);
                const int v2 = __hip_atomic_load(&f2[(tid * 4 + 2) * 16], __ATOMIC_RELAXED, __HIP_MEMORY_SCOPE_AGENT);
                const int v3 = __hip_atomic_load(&f2[(tid * 4 + 3) * 16], __ATOMIC_RELAXED, __HIP_MEMORY_SCOPE_AGENT);
                int mn = v0 < v1 ? v0 : v1;
                mn = mn < v2 ? mn : v2;
                mn = mn < v3 ? mn : v3;
                if (__all(mn >= t + 1)) break;
                __builtin_amdgcn_s_sleep(1);
            }
        }
        __syncthreads();
    }

    // ================= tail: BN + outputs for t = Tt-1 =====================
    {
        const int pR = (Tt - 1) % 3;
        float sc4[4], sh4[4];
        {
            union { u64 u; float f[2]; } ua, ub;
            float sum4[4], sq4[4];
            ua.u = ALD_F((const u64*)&PstSum[pR * 1024 + c4s]);
            ub.u = ALD_F((const u64*)&PstSum[pR * 1024 + c4s + 2]);
            sum4[0] = ua.f[0]; sum4[1] = ua.f[1]; sum4[2] = ub.f[0]; sum4[3] = ub.f[1];
            ua.u = ALD_F((const u64*)&PstSum[pR * 1024 + 512 + c4s]);
            ub.u = ALD_F((const u64*)&PstSum[pR * 1024 + 512 + c4s + 2]);
            sq4[0] = ua.f[0]; sq4[1] = ua.f[1]; sq4[2] = ub.f[0]; sq4[3] = ub.f[1];
            #pragma unroll
            for (int j = 0; j < 4; ++j) {
                const float mu = sum4[j] * (1.f / 256.f);
                const float var = fmaxf(sq4[j] * (1.f / 256.f) - mu * mu, 0.f);
                const float sc = sBg[c4s + j] * rsqrtf(var + EPS_BN);
                sc4[j] = sc; sh4[j] = sBb[c4s + j] - mu * sc;
            }
        }
        float p0 = 0.f, p1 = 0.f;
        #pragma unroll
        for (int i = 0; i < 4; ++i) {
            const int r = rb0 + 4 * i;
            union { u64 u; unsigned short us[4]; } hv;
            hv.u = ALD_F((const u64*)(HrawG + (size_t)(m0 + r) * Hh + c4s));
            float h[4];
            #pragma unroll
            for (int j = 0; j < 4; ++j)
                h[j] = fmaf(bf2f((short)hv.us[j]), sc4[j], sh4[j]);
            if (myng) {
                *(f32x4*)(&out_hs[((size_t)(m0 + r) * Tt + (Tt - 1)) * Hh + c4s]) =
                    (f32x4){h[0], h[1], h[2], h[3]};
            }
            if (r == ng) {
                #pragma unroll
                for (int j = 0; j < 4; ++j) {
                    p0 = fmaf(h[j], sWhy[2 * (c4s + j)], p0);
                    p1 = fmaf(h[j], sWhy[2 * (c4s + j) + 1], p1);
                }
            }
        }
        #pragma unroll
        for (int s = 1; s < 64; s <<= 1) { p0 += __shfl_xor(p0, s); p1 += __shfl_xor(p1, s); }
        if (lane == 0) { ysred[2 * w] = p0; ysred[2 * w + 1] = p1; }
        __syncthreads();
        if (tid == 0) {
            float q0 = 0.f, q1 = 0.f;
            #pragma unroll
            for (int i = 0; i < 8; ++i) { q0 += ysred[2 * i]; q1 += ysred[2 * i + 1]; }
            out_ys[((size_t)(m0 + ng) * Tt + (Tt - 1)) * Oo + 0] = softplusf_(q0 + bhy0);
            out_ys[((size_t)(m0 + ng) * Tt + (Tt - 1)) * Oo + 1] = softplusf_(q1 + bhy1);
        }
    }
}

// ---------------------------------------------------------------------------
extern "C" void kernel_launch(void* const* d_in, const int* in_sizes, int n_in,
                              void* d_out, int out_size, void* d_ws, size_t ws_size,
                              hipStream_t stream)
{
    const float* input  = (const float*)d_in[0];
    const float* xmean  = (const float*)d_in[1];
    const float* W_dg_x = (const float*)d_in[2];
    const float* b_dg_x = (const float*)d_in[3];
    const float* W_dg_h = (const float*)d_in[4];
    const float* b_dg_h = (const float*)d_in[5];
    const float* W_xz   = (const float*)d_in[6];
    const float* W_hz   = (const float*)d_in[7];
    const float* W_mz   = (const float*)d_in[8];
    const float* b_z    = (const float*)d_in[9];
    const float* W_xr   = (const float*)d_in[10];
    const float* W_hr   = (const float*)d_in[11];
    const float* W_mr   = (const float*)d_in[12];
    const float* b_r    = (const float*)d_in[13];
    const float* W_xh   = (const float*)d_in[14];
    const float* W_hh   = (const float*)d_in[15];
    const float* W_mh   = (const float*)d_in[16];
    const float* b_h    = (const float*)d_in[17];
    const float* W_hy   = (const float*)d_in[18];
    const float* b_hy   = (const float*)d_in[19];
    const float* bn_g   = (const float*)d_in[20];
    const float* bn_b   = (const float*)d_in[21];

    float* out_ys = (float*)d_out;
    float* out_hs = out_ys + (size_t)Bb * Tt * Oo;

    char* p = (char*)d_ws;
    float* Xall = (float*)p;            p += (size_t)TBr * Ii * 4;
    short* Mall = (short*)p;            p += (size_t)TBr * Ii * 2;
    short* Dall = (short*)p;            p += (size_t)TBr * Ii * 2;
    short* Gxb  = (short*)p;            p += (size_t)TBr * Ii * 2;
    short* Ghb  = (short*)p;            p += (size_t)TBr * Hh * 2;
    short* Xe   = (short*)p;            p += (size_t)TBr * Ii * 2;
    short* Wc1T = (short*)p;            p += (size_t)1024 * 768 * 2;
    short* Wc2T = (short*)p;            p += (size_t)512 * 768 * 2;
    short* WdgxT= (short*)p;            p += (size_t)128 * 128 * 2;
    short* WdghT= (short*)p;            p += (size_t)512 * 128 * 2;
    float* bias1= (float*)p;            p += 1024 * 4;
    short* rhG  = (short*)p;            p += (size_t)Bb * Hh * 2;
    short* HrawG= (short*)p;            p += (size_t)Bb * Hh * 2;
    float* PstSum=(float*)p;            p += 3 * 1024 * 4;
    int*   f1   = (int*)p;              p += 256 * 16 * 4;
    int*   f2   = (int*)p;              p += 256 * 16 * 4;

    hipMemsetAsync(f1, 0, 256 * 16 * 4, stream);
    hipMemsetAsync(f2, 0, 256 * 16 * 4, stream);
    hipMemsetAsync(PstSum, 0, 3 * 1024 * 4, stream);

    repack_kernel<<<dim3(Tt / 32, Ii / 32, Bb * 3), dim3(32, 32), 0, stream>>>(input, Xall, Mall, Dall);

    {
        const int total = 1024 * 768 + 512 * 768 + 128 * 128 + 512 * 128 + 1024;
        pack_weights_kernel<<<(total + 255) / 256, 256, 0, stream>>>(
            W_dg_x, W_dg_h,
            W_xz, W_hz, W_mz, b_z,
            W_xr, W_hr, W_mr, b_r,
            W_xh, W_hh, W_mh,
            Wc1T, Wc2T, WdgxT, WdghT, bias1);
    }

    gdecay_kernel<<<dim3(TBr / 32, Ii / 64), 64, 0, stream>>>(Dall, WdgxT, b_dg_x, Gxb, Ii);
    gdecay_kernel<<<dim3(TBr / 32, Hh / 64), 64, 0, stream>>>(Dall, WdghT, b_dg_h, Ghb, Hh);

    xeff_scan_kernel<<<(Bb * Ii) / 256, 256, 0, stream>>>(Xall, Mall, Gxb, xmean, Xe);

    grud_persistent<<<256, 512, 0, stream>>>(
        Xe, Mall, Ghb, Wc1T, Wc2T, bias1, b_h, bn_g, bn_b,
        W_hy, b_hy, rhG, HrawG, PstSum, f1, f2, out_hs, out_ys);
}